// Round 15
// baseline (149.020 us; speedup 1.0000x reference)
//
#include <hip/hip_runtime.h>
#include <hip/hip_bf16.h>
#include <stdint.h>

typedef short v8s __attribute__((ext_vector_type(8)));
typedef float v4f __attribute__((ext_vector_type(4)));

#define TPB 1024

// ---- LDS layout (bytes) ----
// X0 [896][80B] no-swz       @0        71,680   (P1 scatter out, P2 in; 80B rows: bank period 8)
// EMB f32[64][16]            @73,728    4,096   (P1 only; inside X2 region, dead by P3)
// X1 [832][64B] swz&3        @106,496  53,248   (P2 out, P3 in)
// X2 [832][128B] swz&7       @0       106,496   (P3 out, P4 in; X0 dead)
// X3 [768][64B] swz&3        @106,496  49,152   (P4 out; X1 dead)
// Ya/Yb f32                  @0/@16,384          (P5+; X2 dead)
// MK  u32[128] room masks    @159,744     512   (persistent)
// CH8 u8[64][36] ch1-8 bits  @160,256   2,304   (persistent)
// RPL int[128] positions     @162,560     512   (persistent)
// MW  u32[112] coverage      @163,072     448   (P1 only)
#define X0_OFF 0
#define EMB_OFF 73728
#define X1_OFF 106496
#define X2_OFF 0
#define X3_OFF 106496
#define YA_OFF 0
#define YB_OFF 16384
#define MK_OFF 159744
#define CH8_OFF 160256
#define RPL_OFF 162560
#define MW_OFF 163072
#define SMEM_BYTES 163520

// ws fragment bases (16B units): conv0 50 frags, conv1 36, conv2 72 (x64 lanes)
#define WS0_U 0
#define WS1_U 3200
#define WS2_U 5504
#define WS_UNITS 10112

__device__ __forceinline__ uint16_t f2b(float f) {
    __hip_bfloat16 h = __float2bfloat16(f);
    return *reinterpret_cast<uint16_t*>(&h);
}
__device__ __forceinline__ uint32_t pkbf(float lo, float hi) {
    return (uint32_t)f2b(lo) | ((uint32_t)f2b(hi) << 16);
}
__device__ __forceinline__ float b2f(uint16_t h) {
    return __uint_as_float(((uint32_t)h) << 16);
}

// ---------------- weight prep: pack A-fragments (bf16) into d_ws ----------------
__global__ void prep_weights(const float* __restrict__ w0,
                             const float* __restrict__ w1,
                             const float* __restrict__ w2,
                             uint8_t* __restrict__ ws)
{
    int u = blockIdx.x * 256 + threadIdx.x;
    if (u >= WS_UNITS) return;
    int l = u & 63, fid = u >> 6;
    const float* src; int IC, KS_, t, kf, m;
    if (fid < 50)      { src = w0; IC = 26; KS_ = 5; t = fid >> 1; kf = 0; m = fid & 1; }
    else if (fid < 86) { int v = fid - 50; src = w1; IC = 32; KS_ = 3; t = v >> 2; kf = 0; m = v & 3; }
    else               { int v = fid - 86; src = w2; IC = 64; KS_ = 3; t = v >> 3; kf = (v >> 2) & 1; m = v & 3; }
    int oc = m * 16 + (l & 15);
    int kb = kf * 32 + ((l >> 4) * 8);
    int ky = t / KS_, kx = t - ky * KS_;
    v8s out;
#pragma unroll
    for (int j = 0; j < 8; ++j) {
        int k = kb + j;
        float v = (k < IC) ? src[((oc * IC + k) * KS_ + ky) * KS_ + kx] : 0.f;
        out[j] = (short)f2b(v);
    }
    ((v8s*)ws)[u] = out;
}

// ---------------- conv core: one k-half sweep (KSEL selects fragment slot / B half) ----------------
template<int MT, int FRAGK, int KSEL, int TAPS, int KS, int PAD,
         int IN_OFF, int IN_STRIDE, int IN_MSK, int IN_ROWS, int WS_BASE, int MT_TOT>
__device__ __forceinline__ void conv_core(const uint8_t* smem, const v8s* __restrict__ wsv,
                                          int l, const int* px, const int* py,
                                          v4f (&acc)[MT][3])
{
    const int kgoff = ((l >> 4) << 4) + KSEL * 64;
    for (int t = 0; t < TAPS; ++t) {
        const int ky = t / KS, kx = t - ky * KS;
        const int dx = ky - PAD, dy = kx - PAD;
        v8s af[MT];
#pragma unroll
        for (int m = 0; m < MT; ++m)
            af[m] = wsv[WS_BASE + ((t * FRAGK + KSEL) * MT_TOT + m) * 64 + l];
#pragma unroll
        for (int i = 0; i < 3; ++i) {
            const int xi = px[i] + dx;
            const int rowp = xi * IN_ROWS + py[i] + dy + PAD;
            int a = rowp * IN_STRIDE + kgoff;
            if (IN_MSK) a ^= (rowp & IN_MSK) << 4;
            a = ((unsigned)xi < 32u) ? a : kgoff;       // x OOB -> zeroed row 0
            a += IN_OFF;
            const v8s bf = *(const v8s*)(smem + a);
#pragma unroll
            for (int m = 0; m < MT; ++m)
                acc[m][i] = __builtin_amdgcn_mfma_f32_16x16x32_bf16(af[m], bf, acc[m][i], 0, 0, 0);
        }
    }
}

// ---------------- conv epilogue: bias+relu+bf16 pack, packed b64 stores ----------------
template<int MTOT, int M0, int M1, int OUT_OFF, int OUT_SH, int OUT_ROWS, int OUT_PAD>
__device__ __forceinline__ void conv_epi(uint8_t* smem, const float* __restrict__ bias,
                                         v4f (&acc)[MTOT][3], const int* px, const int* py, int kg)
{
    constexpr int MSK = (OUT_SH == 7) ? 7 : 3;
#pragma unroll
    for (int m = M0; m < M1; ++m) {
        const float* bp = bias + m * 16 + kg * 4;
        const float bb0 = bp[0], bb1 = bp[1], bb2 = bp[2], bb3 = bp[3];
#pragma unroll
        for (int i = 0; i < 3; ++i) {
            const float v0 = fmaxf(acc[m][i][0] + bb0, 0.f);
            const float v1 = fmaxf(acc[m][i][1] + bb1, 0.f);
            const float v2 = fmaxf(acc[m][i][2] + bb2, 0.f);
            const float v3 = fmaxf(acc[m][i][3] + bb3, 0.f);
            uint2 pk;
            pk.x = pkbf(v0, v1);
            pk.y = pkbf(v2, v3);
            const int rowp = px[i] * OUT_ROWS + py[i] + OUT_PAD;
            const int coff = (m - M0) * 32 + (kg << 3);
            const int a = OUT_OFF + (((rowp << OUT_SH) | coff) ^ ((rowp & MSK) << 4));
            *(uint2*)(smem + a) = pk;
        }
    }
}

// ---------------- gather one conv2 half via register bitmask (256 threads) ----------------
__device__ __forceinline__ void gather_half(const uint8_t* smem,
                                            const uint32_t* __restrict__ mk,
                                            const int* __restrict__ rpl,
                                            int gr, int gl, float* yreg)
{
    const int pxr = rpl[gr * 2], pyr = rpl[gr * 2 + 1];
    const uint32_t mlo = mk[gr * 2], mhi = mk[gr * 2 + 1];
    float s0=0,s1=0,s2=0,s3=0,s4=0,s5=0,s6=0,s7=0;
#pragma unroll
    for (int cell = 0; cell < 36; ++cell) {
        const uint32_t w = (cell < 32) ? mlo : mhi;
        if ((w >> (cell & 31)) & 1u) {
            const int p = (pxr + cell / 6) * 24 + pyr + (cell % 6);
            const v8s v = *(const v8s*)(smem + X3_OFF +
                (((p << 6) | (gl << 4)) ^ ((p & 3) << 4)));
            s0 += b2f((uint16_t)v[0]);
            s1 += b2f((uint16_t)v[1]);
            s2 += b2f((uint16_t)v[2]);
            s3 += b2f((uint16_t)v[3]);
            s4 += b2f((uint16_t)v[4]);
            s5 += b2f((uint16_t)v[5]);
            s6 += b2f((uint16_t)v[6]);
            s7 += b2f((uint16_t)v[7]);
        }
    }
    yreg[0]=s0; yreg[1]=s1; yreg[2]=s2; yreg[3]=s3;
    yreg[4]=s4; yreg[5]=s5; yreg[6]=s6; yreg[7]=s7;
}

// ---------------- MLP layer (f32), 1024 threads: 16 groups x 4 outputs ----------------
template<bool RELU>
__device__ __forceinline__ void mlp_layer(uint8_t* smem, int inoff, int outoff,
                                          const float* __restrict__ W,
                                          const float* __restrict__ bias, int tid)
{
    const int og = tid >> 6, r = tid & 63;
    const int ogs = __builtin_amdgcn_readfirstlane(og);
    const int swz = (r & 7) << 4;
    float acc[4];
#pragma unroll
    for (int oo = 0; oo < 4; ++oo) acc[oo] = bias[ogs * 4 + oo];
    const float* Wb = W + ogs * 4 * 64;
#pragma unroll
    for (int cg = 0; cg < 16; ++cg) {
        const v4f v = *(const v4f*)(smem + inoff + ((r * 256 + cg * 16) ^ swz));
#pragma unroll
        for (int oo = 0; oo < 4; ++oo) {
            const float* wr = Wb + oo * 64 + cg * 4;
            acc[oo] = fmaf(wr[0], v[0], acc[oo]);
            acc[oo] = fmaf(wr[1], v[1], acc[oo]);
            acc[oo] = fmaf(wr[2], v[2], acc[oo]);
            acc[oo] = fmaf(wr[3], v[3], acc[oo]);
        }
    }
    if (RELU)
#pragma unroll
        for (int oo = 0; oo < 4; ++oo) acc[oo] = fmaxf(acc[oo], 0.f);
    const v4f o0 = {acc[0], acc[1], acc[2], acc[3]};
    *(v4f*)(smem + outoff + ((r * 256 + ogs * 16) ^ swz)) = o0;
}

// ---------------- fused main kernel: one block (16 waves) per sample ----------------
__global__ __launch_bounds__(TPB)
void fused_main(const int* __restrict__ rpos,
                const float* __restrict__ rooms,
                const float* __restrict__ emb,
                const float* __restrict__ b0, const float* __restrict__ b1,
                const float* __restrict__ b2,
                const float* __restrict__ rw0, const float* __restrict__ rb0,
                const float* __restrict__ rw1, const float* __restrict__ rb1,
                const float* __restrict__ rw2, const float* __restrict__ rb2,
                const uint8_t* __restrict__ ws,
                float* __restrict__ out)
{
    __shared__ __align__(16) uint8_t smem[SMEM_BYTES];
    const int tid = threadIdx.x, n = blockIdx.x;
    const int* rp = rpos + n * 128;
    const v8s* wsv = (const v8s*)ws;
    uint32_t* mk  = (uint32_t*)(smem + MK_OFF);
    uint8_t*  ch8 = smem + CH8_OFF;
    int*      rpl = (int*)(smem + RPL_OFF);
    uint32_t* mw  = (uint32_t*)(smem + MW_OFF);
    float*    embl = (float*)(smem + EMB_OFF);

    // ---- P0: stage bitmasks / emb / positions into LDS ----
    embl[tid] = emb[tid];                                   // 64*16 = 1024 floats
    if (tid < 112) mw[tid] = 0;
    if (tid >= 128 && tid < 256) mk[tid - 128] = 0;
    if (tid >= 256 && tid < 384) rpl[tid - 256] = rp[tid - 256];
    __syncthreads();
    if (tid < 64) {                                         // coverage masks
        const int pxr = rpl[2 * tid], pyr = rpl[2 * tid + 1];
        const uint32_t bit = 1u << (tid & 31);
        const int xb = (tid >> 5) * 32, yb = 64 + (tid >> 5) * 24;
#pragma unroll
        for (int i = 0; i < 6; ++i) atomicOr(&mw[xb + pxr + i], bit);
#pragma unroll
        for (int j = 0; j < 6; ++j) atomicOr(&mw[yb + pyr + j], bit);
    }
    for (int q = tid; q < 2304; q += TPB) {                 // room bitmasks (rooms ∈ {0,1})
        const int r = (q * 1821) >> 16;                     // q / 36
        const int cell = q - r * 36;
        const float* base = rooms + r * 324 + cell;
        uint32_t bits = 0;
#pragma unroll
        for (int c = 1; c < 9; ++c)
            bits |= (base[c * 36] != 0.f ? 1u : 0u) << (c - 1);
        ch8[q] = (uint8_t)bits;
        if (base[0] != 0.f) atomicOr(&mk[r * 2 + (cell >> 5)], 1u << (cell & 31));
    }
    __syncthreads();

    // ---- P1: scatter via bitmasks (no global loads in the loop); X0 rows 80B ----
    if (tid < 768) {
        const int x = (tid * 2731) >> 16;
        const int y = tid - x * 24;
        float a[26];
#pragma unroll
        for (int c = 0; c < 26; ++c) a[c] = 0.f;
        a[9] = 1.f;
        uint32_t mlo = mw[x] & mw[64 + y];
        uint32_t mhi = mw[32 + x] & mw[88 + y];
#pragma unroll 1
        for (int half = 0; half < 2; ++half) {
            uint32_t mm = half ? mhi : mlo;
            const int rb = half ? 32 : 0;
            while (mm) {
                const int r = rb + __builtin_ctz(mm);
                mm &= mm - 1;
                const int cell = (x - rpl[2 * r]) * 6 + (y - rpl[2 * r + 1]);
                const uint32_t w = mk[r * 2 + (cell >> 5)];
                if ((w >> (cell & 31)) & 1u) {
                    a[0] += 1.f;
                    const uint32_t bits = ch8[r * 36 + cell];
#pragma unroll
                    for (int c = 0; c < 8; ++c)
                        a[1 + c] += (float)((bits >> c) & 1u);
                    const float* er = embl + r * 16;
#pragma unroll
                    for (int e = 0; e < 16; ++e) a[10 + e] += er[e];
                }
            }
        }
        const int row = x * 28 + y + 2;
#pragma unroll
        for (int cg = 0; cg < 4; ++cg) {
            float c[8];
#pragma unroll
            for (int j = 0; j < 8; ++j) {
                const int ci = cg * 8 + j;
                c[j] = (ci < 26) ? a[(ci < 26) ? ci : 0] : 0.f;
            }
            uint2 p0, p1;
            p0.x = pkbf(c[0], c[1]); p0.y = pkbf(c[2], c[3]);
            p1.x = pkbf(c[4], c[5]); p1.y = pkbf(c[6], c[7]);
            const int a0 = X0_OFF + row * 80 + cg * 16;
            *(uint2*)(smem + a0)     = p0;
            *(uint2*)(smem + a0 + 8) = p1;
        }
    } else {
        const int base = (tid - 768) * 2;                   // X0 y-pad rows
#pragma unroll
        for (int k = 0; k < 2; ++k) {
            const int u = base + k;
            const int rowi = u >> 2, slot = u & 3;
            const int x = rowi >> 2, yp = rowi & 3;
            const int row = x * 28 + ((yp < 2) ? yp : yp + 24);
            *(v8s*)(smem + X0_OFF + row * 80 + slot * 16) = (v8s){0,0,0,0,0,0,0,0};
        }
    }
    __syncthreads();

    // per-thread MFMA geometry
    const int l = tid & 63, wv = tid >> 6, kg = l >> 4;
    int px[3], py[3];
#pragma unroll
    for (int i = 0; i < 3; ++i) {
        const int p = (wv + 16 * i) * 16 + (l & 15);
        const int x = (p * 2731) >> 16;
        px[i] = x; py[i] = p - x * 24;
    }

    // ---- P2: conv0 (26->32, 5x5) + X1 pad zero ----
    {
        if (tid < 256) {
            const int rowi = tid >> 2, slot = tid & 3;
            const int x = rowi >> 1;
            const int rowp = x * 26 + ((rowi & 1) ? 25 : 0);
            *(v8s*)(smem + X1_OFF + (((rowp << 6) | (slot << 4)) ^ ((rowp & 3) << 4))) =
                (v8s){0,0,0,0,0,0,0,0};
        }
        v4f acc[2][3];
#pragma unroll
        for (int m = 0; m < 2; ++m)
#pragma unroll
            for (int i = 0; i < 3; ++i) acc[m][i] = (v4f){0.f,0.f,0.f,0.f};
        conv_core<2,1,0,25,5,2, X0_OFF,80,0,28, WS0_U,2>(smem, wsv, l, px, py, acc);
        conv_epi<2,0,2, X1_OFF,6,26,1>(smem, b0, acc, px, py, kg);
    }
    __syncthreads();

    // ---- P3: conv1 (32->64, 3x3) + X2 pad zero ----
    {
        if (tid < 512) {
            const int rowi = tid >> 3, slot = tid & 7;
            const int x = rowi >> 1;
            const int rowp = x * 26 + ((rowi & 1) ? 25 : 0);
            *(v8s*)(smem + X2_OFF + (((rowp << 7) | (slot << 4)) ^ ((rowp & 7) << 4))) =
                (v8s){0,0,0,0,0,0,0,0};
        }
        v4f acc[4][3];
#pragma unroll
        for (int m = 0; m < 4; ++m)
#pragma unroll
            for (int i = 0; i < 3; ++i) acc[m][i] = (v4f){0.f,0.f,0.f,0.f};
        conv_core<4,1,0,9,3,1, X1_OFF,64,3,26, WS1_U,4>(smem, wsv, l, px, py, acc);
        conv_epi<4,0,4, X2_OFF,7,26,1>(smem, b1, acc, px, py, kg);
    }
    __syncthreads();

    // ---- P4: conv2 (64->64, 3x3) as two KF=1 k-half sweeps into one acc ----
    float yregA[8], yregB[8];
    {
        v4f acc[4][3];
#pragma unroll
        for (int m = 0; m < 4; ++m)
#pragma unroll
            for (int i = 0; i < 3; ++i) acc[m][i] = (v4f){0.f,0.f,0.f,0.f};
        conv_core<4,2,0,9,3,1, X2_OFF,128,7,26, WS2_U,4>(smem, wsv, l, px, py, acc);  // k 0..31
        conv_core<4,2,1,9,3,1, X2_OFF,128,7,26, WS2_U,4>(smem, wsv, l, px, py, acc);  // k 32..63
        conv_epi<4,0,2, X3_OFF,6,24,0>(smem, b2, acc, px, py, kg);   // X3 disjoint from X2
        __syncthreads();
        if (tid < 256) gather_half(smem, mk, rpl, tid >> 2, tid & 3, yregA);
        __syncthreads();
        conv_epi<4,2,4, X3_OFF,6,24,0>(smem, b2, acc, px, py, kg);
        __syncthreads();
        if (tid < 256) gather_half(smem, mk, rpl, tid >> 2, tid & 3, yregB);
        __syncthreads();
    }

    // ---- P5: assemble Y f32 [r][c] (swizzled rows) ----
    if (tid < 256) {
        const int gr = tid >> 2, gl = tid & 3;
        const int swz = (gr & 7) << 4;
        const int baseA = gr * 256 + gl * 32;
        const int baseB = baseA + 128;
        *(v4f*)(smem + YA_OFF + (baseA ^ swz))        = (v4f){yregA[0], yregA[1], yregA[2], yregA[3]};
        *(v4f*)(smem + YA_OFF + ((baseA + 16) ^ swz)) = (v4f){yregA[4], yregA[5], yregA[6], yregA[7]};
        *(v4f*)(smem + YA_OFF + (baseB ^ swz))        = (v4f){yregB[0], yregB[1], yregB[2], yregB[3]};
        *(v4f*)(smem + YA_OFF + ((baseB + 16) ^ swz)) = (v4f){yregB[4], yregB[5], yregB[6], yregB[7]};
    }
    __syncthreads();

    // ---- P6: 3-layer room MLP (f32), all in LDS ----
    mlp_layer<true >(smem, YA_OFF, YB_OFF, rw0, rb0, tid);
    __syncthreads();
    mlp_layer<true >(smem, YB_OFF, YA_OFF, rw1, rb1, tid);
    __syncthreads();
    mlp_layer<false>(smem, YA_OFF, YB_OFF, rw2, rb2, tid);
    __syncthreads();

    // ---- P7: coalesced output store ----
    {
        const int r = tid >> 4, cg = tid & 15;
        const int swz = (r & 7) << 4;
        const v4f v = *(const v4f*)(smem + YB_OFF + ((r * 256 + cg * 16) ^ swz));
        *(v4f*)(out + n * 4096 + r * 64 + cg * 4) = v;
    }
}

extern "C" void kernel_launch(void* const* d_in, const int* in_sizes, int n_in,
                              void* d_out, int out_size, void* d_ws, size_t ws_size,
                              hipStream_t stream) {
    const int*   rpos  = (const int*)  d_in[0];
    const float* rooms = (const float*)d_in[1];
    const float* emb   = (const float*)d_in[2];
    const float* w0    = (const float*)d_in[3];
    const float* b0    = (const float*)d_in[4];
    const float* w1    = (const float*)d_in[5];
    const float* b1    = (const float*)d_in[6];
    const float* w2    = (const float*)d_in[7];
    const float* b2    = (const float*)d_in[8];
    const float* rw0   = (const float*)d_in[9];
    const float* rb0   = (const float*)d_in[10];
    const float* rw1   = (const float*)d_in[11];
    const float* rb1   = (const float*)d_in[12];
    const float* rw2   = (const float*)d_in[13];
    const float* rb2   = (const float*)d_in[14];
    float* out = (float*)d_out;
    uint8_t* ws = (uint8_t*)d_ws;

    const int n = in_sizes[0] / 128;   // samples (512)
    hipLaunchKernelGGL(prep_weights, dim3((WS_UNITS + 255) / 256), dim3(256), 0, stream,
                       w0, w1, w2, ws);
    hipLaunchKernelGGL(fused_main, dim3(n), dim3(TPB), 0, stream,
                       rpos, rooms, emb, b0, b1, b2,
                       rw0, rb0, rw1, rb1, rw2, rb2, ws, out);
}

// Round 16
// 118.081 us; speedup vs baseline: 1.2620x; 1.2620x over previous
//
#include <hip/hip_runtime.h>
#include <hip/hip_bf16.h>
#include <stdint.h>

typedef short v8s __attribute__((ext_vector_type(8)));
typedef float v4f __attribute__((ext_vector_type(4)));

#define TPB 1024

// ---- LDS layout (bytes) ----
// X0 [896][64B] swz&3        @0        57,344   (P1 scatter out, P2 in)
// X1 [832][64B] swz&3        @106,496  53,248   (P2 out, P3 in)
// X2 [832][128B] swz&7       @0       106,496   (P3 out, P4 in; X0 dead)
// X3 [768][64B] swz&3        @106,496  49,152   (P4 out; X1 dead)
// Ya/Yb f32                  @0/@16,384          (P5+; X2 dead)
// EMB f32[64][16]            @57,344    4,096   (P1 only; overwritten by X2)
// MK  u32[128] room masks    @159,744     512   (persistent)
// CH8 u8[64][36] ch1-8 bits  @160,256   2,304   (persistent)
// RPL int[128] positions     @162,560     512   (persistent)
// MW  u32[112] coverage      @163,072     448   (P1 only)
#define X0_OFF 0
#define X1_OFF 106496
#define X2_OFF 0
#define X3_OFF 106496
#define YA_OFF 0
#define YB_OFF 16384
#define EMB_OFF 57344
#define MK_OFF 159744
#define CH8_OFF 160256
#define RPL_OFF 162560
#define MW_OFF 163072
#define SMEM_BYTES 163520

// ws fragment bases (16B units): conv0 50 frags, conv1 36, conv2 72 (x64 lanes)
#define WS0_U 0
#define WS1_U 3200
#define WS2_U 5504
#define WS_UNITS 10112
#define WS_W_BYTES (WS_UNITS * 16)      // 161,792
// sample-independent bitmasks, precomputed once:
#define MKG_OFF  WS_W_BYTES             // u32[128]  @161,792
#define CH8G_OFF (WS_W_BYTES + 512)     // u8[2304]  @162,304

__device__ __forceinline__ uint16_t f2b(float f) {
    __hip_bfloat16 h = __float2bfloat16(f);
    return *reinterpret_cast<uint16_t*>(&h);
}
__device__ __forceinline__ uint32_t pkbf(float lo, float hi) {
    return (uint32_t)f2b(lo) | ((uint32_t)f2b(hi) << 16);
}
__device__ __forceinline__ float b2f(uint16_t h) {
    return __uint_as_float(((uint32_t)h) << 16);
}

// ---------------- weight prep: pack A-fragments (bf16) into d_ws ----------------
__global__ void prep_weights(const float* __restrict__ w0,
                             const float* __restrict__ w1,
                             const float* __restrict__ w2,
                             uint8_t* __restrict__ ws)
{
    int u = blockIdx.x * 256 + threadIdx.x;
    if (u >= WS_UNITS) return;
    int l = u & 63, fid = u >> 6;
    const float* src; int IC, KS_, t, kf, m;
    if (fid < 50)      { src = w0; IC = 26; KS_ = 5; t = fid >> 1; kf = 0; m = fid & 1; }
    else if (fid < 86) { int v = fid - 50; src = w1; IC = 32; KS_ = 3; t = v >> 2; kf = 0; m = v & 3; }
    else               { int v = fid - 86; src = w2; IC = 64; KS_ = 3; t = v >> 3; kf = (v >> 2) & 1; m = v & 3; }
    int oc = m * 16 + (l & 15);
    int kb = kf * 32 + ((l >> 4) * 8);
    int ky = t / KS_, kx = t - ky * KS_;
    v8s out;
#pragma unroll
    for (int j = 0; j < 8; ++j) {
        int k = kb + j;
        float v = (k < IC) ? src[((oc * IC + k) * KS_ + ky) * KS_ + kx] : 0.f;
        out[j] = (short)f2b(v);
    }
    ((v8s*)ws)[u] = out;
}

// ---------------- mask prep: sample-independent room bitmasks (one block) ----------------
__global__ void prep_masks(const float* __restrict__ rooms, uint8_t* __restrict__ ws)
{
    const int t = threadIdx.x;                       // 256 threads
    uint32_t* mkg = (uint32_t*)(ws + MKG_OFF);
    uint8_t*  ch8g = ws + CH8G_OFF;
    for (int q = t; q < 2304; q += 256) {            // channel bits (rooms ∈ {0,1})
        const int r = (q * 1821) >> 16;              // q / 36
        const int cell = q - r * 36;
        const float* base = rooms + r * 324 + cell;
        uint32_t bits = 0;
#pragma unroll
        for (int c = 1; c < 9; ++c)
            bits |= (base[c * 36] != 0.f ? 1u : 0u) << (c - 1);
        ch8g[q] = (uint8_t)bits;
    }
    if (t < 128) {                                   // mask-channel bits
        const int r = t >> 1, h = t & 1;
        const float* rr = rooms + r * 324;
        uint32_t m = 0;
        const int c0 = h * 32, c1 = h ? 36 : 32;
        for (int cell = c0; cell < c1; ++cell)
            if (rr[cell] != 0.f) m |= 1u << (cell - c0);
        mkg[t] = m;
    }
}

// ---------------- conv core: tap-decomposed implicit GEMM on MFMA ----------------
template<int MT, int KF, int TAPS, int KS, int PAD,
         int IN_OFF, int IN_SH, int IN_ROWS, int WS_BASE, int MT_TOT>
__device__ __forceinline__ void conv_core(const uint8_t* smem, const v8s* __restrict__ wsv,
                                          int l, const int* px, const int* py,
                                          v4f (&acc)[MT][3])
{
    const int kgoff = ((l >> 4) << 4);
    constexpr int MSK = (IN_SH == 7) ? 7 : 3;
    for (int t = 0; t < TAPS; ++t) {
        const int ky = t / KS, kx = t - ky * KS;
        const int dx = ky - PAD, dy = kx - PAD;
        v8s af[MT][KF];
#pragma unroll
        for (int m = 0; m < MT; ++m)
#pragma unroll
            for (int kf = 0; kf < KF; ++kf)
                af[m][kf] = wsv[WS_BASE + ((t * KF + kf) * MT_TOT + m) * 64 + l];
#pragma unroll
        for (int i = 0; i < 3; ++i) {
            const int xi = px[i] + dx;
            const int rowp = xi * IN_ROWS + py[i] + dy + PAD;
            int a = ((rowp << IN_SH) | kgoff) ^ ((rowp & MSK) << 4);
            a = ((unsigned)xi < 32u) ? a : kgoff;
            a += IN_OFF;
            const v8s bf0 = *(const v8s*)(smem + a);
#pragma unroll
            for (int m = 0; m < MT; ++m)
                acc[m][i] = __builtin_amdgcn_mfma_f32_16x16x32_bf16(af[m][0], bf0, acc[m][i], 0, 0, 0);
            if (KF == 2) {
                const v8s bf1 = *(const v8s*)(smem + (a ^ 64));
#pragma unroll
                for (int m = 0; m < MT; ++m)
                    acc[m][i] = __builtin_amdgcn_mfma_f32_16x16x32_bf16(af[m][1], bf1, acc[m][i], 0, 0, 0);
            }
        }
    }
}

// ---------------- conv epilogue: bias+relu+bf16 pack, packed b64 stores ----------------
template<int MTOT, int M0, int M1, int OUT_OFF, int OUT_SH, int OUT_ROWS, int OUT_PAD>
__device__ __forceinline__ void conv_epi(uint8_t* smem, const float* __restrict__ bias,
                                         v4f (&acc)[MTOT][3], const int* px, const int* py, int kg)
{
    constexpr int MSK = (OUT_SH == 7) ? 7 : 3;
#pragma unroll
    for (int m = M0; m < M1; ++m) {
        const float* bp = bias + m * 16 + kg * 4;
        const float bb0 = bp[0], bb1 = bp[1], bb2 = bp[2], bb3 = bp[3];
#pragma unroll
        for (int i = 0; i < 3; ++i) {
            const float v0 = fmaxf(acc[m][i][0] + bb0, 0.f);
            const float v1 = fmaxf(acc[m][i][1] + bb1, 0.f);
            const float v2 = fmaxf(acc[m][i][2] + bb2, 0.f);
            const float v3 = fmaxf(acc[m][i][3] + bb3, 0.f);
            uint2 pk;
            pk.x = pkbf(v0, v1);
            pk.y = pkbf(v2, v3);
            const int rowp = px[i] * OUT_ROWS + py[i] + OUT_PAD;
            const int coff = (m - M0) * 32 + (kg << 3);
            const int a = OUT_OFF + (((rowp << OUT_SH) | coff) ^ ((rowp & MSK) << 4));
            *(uint2*)(smem + a) = pk;
        }
    }
}

// ---------------- gather one conv2 half via register bitmask (256 threads) ----------------
__device__ __forceinline__ void gather_half(const uint8_t* smem,
                                            const uint32_t* __restrict__ mk,
                                            const int* __restrict__ rpl,
                                            int gr, int gl, float* yreg)
{
    const int pxr = rpl[gr * 2], pyr = rpl[gr * 2 + 1];
    const uint32_t mlo = mk[gr * 2], mhi = mk[gr * 2 + 1];
    float s0=0,s1=0,s2=0,s3=0,s4=0,s5=0,s6=0,s7=0;
#pragma unroll
    for (int cell = 0; cell < 36; ++cell) {
        const uint32_t w = (cell < 32) ? mlo : mhi;
        if ((w >> (cell & 31)) & 1u) {
            const int p = (pxr + cell / 6) * 24 + pyr + (cell % 6);
            const v8s v = *(const v8s*)(smem + X3_OFF +
                (((p << 6) | (gl << 4)) ^ ((p & 3) << 4)));
            s0 += b2f((uint16_t)v[0]);
            s1 += b2f((uint16_t)v[1]);
            s2 += b2f((uint16_t)v[2]);
            s3 += b2f((uint16_t)v[3]);
            s4 += b2f((uint16_t)v[4]);
            s5 += b2f((uint16_t)v[5]);
            s6 += b2f((uint16_t)v[6]);
            s7 += b2f((uint16_t)v[7]);
        }
    }
    yreg[0]=s0; yreg[1]=s1; yreg[2]=s2; yreg[3]=s3;
    yreg[4]=s4; yreg[5]=s5; yreg[6]=s6; yreg[7]=s7;
}

// ---------------- MLP layer (f32), 1024 threads: 16 groups x 4 outputs ----------------
template<bool RELU>
__device__ __forceinline__ void mlp_layer(uint8_t* smem, int inoff, int outoff,
                                          const float* __restrict__ W,
                                          const float* __restrict__ bias, int tid)
{
    const int og = tid >> 6, r = tid & 63;
    const int ogs = __builtin_amdgcn_readfirstlane(og);
    const int swz = (r & 7) << 4;
    float acc[4];
#pragma unroll
    for (int oo = 0; oo < 4; ++oo) acc[oo] = bias[ogs * 4 + oo];
    const float* Wb = W + ogs * 4 * 64;
#pragma unroll
    for (int cg = 0; cg < 16; ++cg) {
        const v4f v = *(const v4f*)(smem + inoff + ((r * 256 + cg * 16) ^ swz));
#pragma unroll
        for (int oo = 0; oo < 4; ++oo) {
            const float* wr = Wb + oo * 64 + cg * 4;
            acc[oo] = fmaf(wr[0], v[0], acc[oo]);
            acc[oo] = fmaf(wr[1], v[1], acc[oo]);
            acc[oo] = fmaf(wr[2], v[2], acc[oo]);
            acc[oo] = fmaf(wr[3], v[3], acc[oo]);
        }
    }
    if (RELU)
#pragma unroll
        for (int oo = 0; oo < 4; ++oo) acc[oo] = fmaxf(acc[oo], 0.f);
    const v4f o0 = {acc[0], acc[1], acc[2], acc[3]};
    *(v4f*)(smem + outoff + ((r * 256 + ogs * 16) ^ swz)) = o0;
}

// ---------------- fused main kernel: one block (16 waves) per sample ----------------
__global__ __launch_bounds__(TPB)
void fused_main(const int* __restrict__ rpos,
                const float* __restrict__ rooms,
                const float* __restrict__ emb,
                const float* __restrict__ b0, const float* __restrict__ b1,
                const float* __restrict__ b2,
                const float* __restrict__ rw0, const float* __restrict__ rb0,
                const float* __restrict__ rw1, const float* __restrict__ rb1,
                const float* __restrict__ rw2, const float* __restrict__ rb2,
                const uint8_t* __restrict__ ws,
                float* __restrict__ out)
{
    __shared__ __align__(16) uint8_t smem[SMEM_BYTES];
    const int tid = threadIdx.x, n = blockIdx.x;
    const int* rp = rpos + n * 128;
    const v8s* wsv = (const v8s*)ws;
    uint32_t* mk  = (uint32_t*)(smem + MK_OFF);
    uint8_t*  ch8 = smem + CH8_OFF;
    int*      rpl = (int*)(smem + RPL_OFF);
    uint32_t* mw  = (uint32_t*)(smem + MW_OFF);
    float*    embl = (float*)(smem + EMB_OFF);

    // ---- P0: stage emb/positions + COPY precomputed bitmasks (no rebuild) ----
    embl[tid] = emb[tid];                                   // 64*16 = 1024 floats
    if (tid < 112) mw[tid] = 0;
    if (tid >= 128 && tid < 256) mk[tid - 128] = ((const uint32_t*)(ws + MKG_OFF))[tid - 128];
    if (tid >= 256 && tid < 384) rpl[tid - 256] = rp[tid - 256];
    if (tid >= 384 && tid < 960) ((uint32_t*)ch8)[tid - 384] =
        ((const uint32_t*)(ws + CH8G_OFF))[tid - 384];      // 576 u32 = 2,304 B
    __syncthreads();
    if (tid < 64) {                                         // coverage masks
        const int pxr = rpl[2 * tid], pyr = rpl[2 * tid + 1];
        const uint32_t bit = 1u << (tid & 31);
        const int xb = (tid >> 5) * 32, yb = 64 + (tid >> 5) * 24;
#pragma unroll
        for (int i = 0; i < 6; ++i) atomicOr(&mw[xb + pxr + i], bit);
#pragma unroll
        for (int j = 0; j < 6; ++j) atomicOr(&mw[yb + pyr + j], bit);
    }
    __syncthreads();

    // ---- P1: scatter via bitmasks (no global loads in the loop) ----
    if (tid < 768) {
        const int x = (tid * 2731) >> 16;
        const int y = tid - x * 24;
        float a[26];
#pragma unroll
        for (int c = 0; c < 26; ++c) a[c] = 0.f;
        a[9] = 1.f;
        uint32_t mlo = mw[x] & mw[64 + y];
        uint32_t mhi = mw[32 + x] & mw[88 + y];
#pragma unroll 1
        for (int half = 0; half < 2; ++half) {
            uint32_t mm = half ? mhi : mlo;
            const int rb = half ? 32 : 0;
            while (mm) {
                const int r = rb + __builtin_ctz(mm);
                mm &= mm - 1;
                const int cell = (x - rpl[2 * r]) * 6 + (y - rpl[2 * r + 1]);
                const uint32_t w = mk[r * 2 + (cell >> 5)];
                if ((w >> (cell & 31)) & 1u) {
                    a[0] += 1.f;
                    const uint32_t bits = ch8[r * 36 + cell];
#pragma unroll
                    for (int c = 0; c < 8; ++c)
                        a[1 + c] += (float)((bits >> c) & 1u);
                    const float* er = embl + r * 16;
#pragma unroll
                    for (int e = 0; e < 16; ++e) a[10 + e] += er[e];
                }
            }
        }
        const int row = x * 28 + y + 2;
        const int swz = (row & 3) << 4;
#pragma unroll
        for (int cg = 0; cg < 4; ++cg) {
            float c[8];
#pragma unroll
            for (int j = 0; j < 8; ++j) {
                const int ci = cg * 8 + j;
                c[j] = (ci < 26) ? a[(ci < 26) ? ci : 0] : 0.f;
            }
            uint2 p0, p1;
            p0.x = pkbf(c[0], c[1]); p0.y = pkbf(c[2], c[3]);
            p1.x = pkbf(c[4], c[5]); p1.y = pkbf(c[6], c[7]);
            const int a0 = X0_OFF + (((row << 6) | (cg << 4)) ^ swz);
            *(uint2*)(smem + a0)     = p0;
            *(uint2*)(smem + a0 + 8) = p1;
        }
    } else {
        const int base = (tid - 768) * 2;                   // X0 y-pad rows
#pragma unroll
        for (int k = 0; k < 2; ++k) {
            const int u = base + k;
            const int rowi = u >> 2, slot = u & 3;
            const int x = rowi >> 2, yp = rowi & 3;
            const int row = x * 28 + ((yp < 2) ? yp : yp + 24);
            *(v8s*)(smem + X0_OFF + (((row << 6) | (slot << 4)) ^ ((row & 3) << 4))) =
                (v8s){0,0,0,0,0,0,0,0};
        }
    }
    __syncthreads();

    // per-thread MFMA geometry
    const int l = tid & 63, wv = tid >> 6, kg = l >> 4;
    int px[3], py[3];
#pragma unroll
    for (int i = 0; i < 3; ++i) {
        const int p = (wv + 16 * i) * 16 + (l & 15);
        const int x = (p * 2731) >> 16;
        px[i] = x; py[i] = p - x * 24;
    }

    // ---- P2: conv0 (26->32, 5x5) + X1 pad zero ----
    {
        if (tid < 256) {
            const int rowi = tid >> 2, slot = tid & 3;
            const int x = rowi >> 1;
            const int rowp = x * 26 + ((rowi & 1) ? 25 : 0);
            *(v8s*)(smem + X1_OFF + (((rowp << 6) | (slot << 4)) ^ ((rowp & 3) << 4))) =
                (v8s){0,0,0,0,0,0,0,0};
        }
        v4f acc[2][3];
#pragma unroll
        for (int m = 0; m < 2; ++m)
#pragma unroll
            for (int i = 0; i < 3; ++i) acc[m][i] = (v4f){0.f,0.f,0.f,0.f};
        conv_core<2,1,25,5,2, X0_OFF,6,28, WS0_U,2>(smem, wsv, l, px, py, acc);
        conv_epi<2,0,2, X1_OFF,6,26,1>(smem, b0, acc, px, py, kg);
    }
    __syncthreads();

    // ---- P3: conv1 (32->64, 3x3) + X2 pad zero ----
    {
        if (tid < 512) {
            const int rowi = tid >> 3, slot = tid & 7;
            const int x = rowi >> 1;
            const int rowp = x * 26 + ((rowi & 1) ? 25 : 0);
            *(v8s*)(smem + X2_OFF + (((rowp << 7) | (slot << 4)) ^ ((rowp & 7) << 4))) =
                (v8s){0,0,0,0,0,0,0,0};
        }
        v4f acc[4][3];
#pragma unroll
        for (int m = 0; m < 4; ++m)
#pragma unroll
            for (int i = 0; i < 3; ++i) acc[m][i] = (v4f){0.f,0.f,0.f,0.f};
        conv_core<4,1,9,3,1, X1_OFF,6,26, WS1_U,4>(smem, wsv, l, px, py, acc);
        conv_epi<4,0,4, X2_OFF,7,26,1>(smem, b1, acc, px, py, kg);
    }
    __syncthreads();

    // ---- P4: conv2 (64->64, 3x3) single K-sweep, two-stage epilogue + bit-gather ----
    float yregA[8], yregB[8];
    {
        v4f acc[4][3];
#pragma unroll
        for (int m = 0; m < 4; ++m)
#pragma unroll
            for (int i = 0; i < 3; ++i) acc[m][i] = (v4f){0.f,0.f,0.f,0.f};
        conv_core<4,2,9,3,1, X2_OFF,7,26, WS2_U,4>(smem, wsv, l, px, py, acc);
        conv_epi<4,0,2, X3_OFF,6,24,0>(smem, b2, acc, px, py, kg);   // X3 disjoint from X2
        __syncthreads();
        if (tid < 256) gather_half(smem, mk, rpl, tid >> 2, tid & 3, yregA);
        __syncthreads();
        conv_epi<4,2,4, X3_OFF,6,24,0>(smem, b2, acc, px, py, kg);
        __syncthreads();
        if (tid < 256) gather_half(smem, mk, rpl, tid >> 2, tid & 3, yregB);
        __syncthreads();
    }

    // ---- P5: assemble Y f32 [r][c] (swizzled rows) ----
    if (tid < 256) {
        const int gr = tid >> 2, gl = tid & 3;
        const int swz = (gr & 7) << 4;
        const int baseA = gr * 256 + gl * 32;
        const int baseB = baseA + 128;
        *(v4f*)(smem + YA_OFF + (baseA ^ swz))        = (v4f){yregA[0], yregA[1], yregA[2], yregA[3]};
        *(v4f*)(smem + YA_OFF + ((baseA + 16) ^ swz)) = (v4f){yregA[4], yregA[5], yregA[6], yregA[7]};
        *(v4f*)(smem + YA_OFF + (baseB ^ swz))        = (v4f){yregB[0], yregB[1], yregB[2], yregB[3]};
        *(v4f*)(smem + YA_OFF + ((baseB + 16) ^ swz)) = (v4f){yregB[4], yregB[5], yregB[6], yregB[7]};
    }
    __syncthreads();

    // ---- P6: 3-layer room MLP (f32), all in LDS ----
    mlp_layer<true >(smem, YA_OFF, YB_OFF, rw0, rb0, tid);
    __syncthreads();
    mlp_layer<true >(smem, YB_OFF, YA_OFF, rw1, rb1, tid);
    __syncthreads();
    mlp_layer<false>(smem, YA_OFF, YB_OFF, rw2, rb2, tid);
    __syncthreads();

    // ---- P7: coalesced output store ----
    {
        const int r = tid >> 4, cg = tid & 15;
        const int swz = (r & 7) << 4;
        const v4f v = *(const v4f*)(smem + YB_OFF + ((r * 256 + cg * 16) ^ swz));
        *(v4f*)(out + n * 4096 + r * 64 + cg * 4) = v;
    }
}

extern "C" void kernel_launch(void* const* d_in, const int* in_sizes, int n_in,
                              void* d_out, int out_size, void* d_ws, size_t ws_size,
                              hipStream_t stream) {
    const int*   rpos  = (const int*)  d_in[0];
    const float* rooms = (const float*)d_in[1];
    const float* emb   = (const float*)d_in[2];
    const float* w0    = (const float*)d_in[3];
    const float* b0    = (const float*)d_in[4];
    const float* w1    = (const float*)d_in[5];
    const float* b1    = (const float*)d_in[6];
    const float* w2    = (const float*)d_in[7];
    const float* b2    = (const float*)d_in[8];
    const float* rw0   = (const float*)d_in[9];
    const float* rb0   = (const float*)d_in[10];
    const float* rw1   = (const float*)d_in[11];
    const float* rb1   = (const float*)d_in[12];
    const float* rw2   = (const float*)d_in[13];
    const float* rb2   = (const float*)d_in[14];
    float* out = (float*)d_out;
    uint8_t* ws = (uint8_t*)d_ws;

    const int n = in_sizes[0] / 128;   // samples (512)
    hipLaunchKernelGGL(prep_weights, dim3((WS_UNITS + 255) / 256), dim3(256), 0, stream,
                       w0, w1, w2, ws);
    hipLaunchKernelGGL(prep_masks, dim3(1), dim3(256), 0, stream, rooms, ws);
    hipLaunchKernelGGL(fused_main, dim3(n), dim3(TPB), 0, stream,
                       rpos, rooms, emb, b0, b1, b2,
                       rw0, rb0, rw1, rb1, rw2, rb2, ws, out);
}

// Round 17
// 109.143 us; speedup vs baseline: 1.3654x; 1.0819x over previous
//
#include <hip/hip_runtime.h>
#include <hip/hip_bf16.h>
#include <stdint.h>

typedef short v8s __attribute__((ext_vector_type(8)));
typedef float v4f __attribute__((ext_vector_type(4)));

#define TPB 1024

// ---- LDS layout (bytes) ----
// X0 [896][64B] swz(row>>1)&3 @0        57,344   (P1 scatter out, P2 in)
// X1 [832][64B] swz(row>>1)&3 @106,496  53,248   (P2 out, P3 in)
// X2 [832][128B] swz&7        @0       106,496   (P3 out, P4 in; X0 dead)
// X3 [768][64B] swz(row>>1)&3 @106,496  49,152   (P4 out; X1 dead)
// Ya/Yb f32                   @0/@16,384          (P5+; X2 dead)
// EMB f32[64][16]             @57,344    4,096   (P1 only; overwritten by X2)
// MK  u32[128] room masks     @159,744     512   (persistent)
// CH8 u8[64][36] ch1-8 bits   @160,256   2,304   (persistent)
// RPL int[128] positions      @162,560     512   (persistent)
// MW  u32[112] coverage       @163,072     448   (P1 only)
#define X0_OFF 0
#define X1_OFF 106496
#define X2_OFF 0
#define X3_OFF 106496
#define YA_OFF 0
#define YB_OFF 16384
#define EMB_OFF 57344
#define MK_OFF 159744
#define CH8_OFF 160256
#define RPL_OFF 162560
#define MW_OFF 163072
#define SMEM_BYTES 163520

// ws fragment bases (16B units): conv0 50 frags, conv1 36, conv2 72 (x64 lanes)
#define WS0_U 0
#define WS1_U 3200
#define WS2_U 5504
#define WS_UNITS 10112

// 64B-row swizzle: key on (row>>1)&3 -> 8 distinct banks over 8 consecutive rows
#define SWZ64(row) ((((row) >> 1) & 3) << 4)

__device__ __forceinline__ uint16_t f2b(float f) {
    __hip_bfloat16 h = __float2bfloat16(f);
    return *reinterpret_cast<uint16_t*>(&h);
}
__device__ __forceinline__ uint32_t pkbf(float lo, float hi) {
    return (uint32_t)f2b(lo) | ((uint32_t)f2b(hi) << 16);
}
__device__ __forceinline__ float b2f(uint16_t h) {
    return __uint_as_float(((uint32_t)h) << 16);
}

// ---------------- weight prep: pack A-fragments (bf16) into d_ws ----------------
__global__ void prep_weights(const float* __restrict__ w0,
                             const float* __restrict__ w1,
                             const float* __restrict__ w2,
                             uint8_t* __restrict__ ws)
{
    int u = blockIdx.x * 256 + threadIdx.x;
    if (u >= WS_UNITS) return;
    int l = u & 63, fid = u >> 6;
    const float* src; int IC, KS_, t, kf, m;
    if (fid < 50)      { src = w0; IC = 26; KS_ = 5; t = fid >> 1; kf = 0; m = fid & 1; }
    else if (fid < 86) { int v = fid - 50; src = w1; IC = 32; KS_ = 3; t = v >> 2; kf = 0; m = v & 3; }
    else               { int v = fid - 86; src = w2; IC = 64; KS_ = 3; t = v >> 3; kf = (v >> 2) & 1; m = v & 3; }
    int oc = m * 16 + (l & 15);
    int kb = kf * 32 + ((l >> 4) * 8);
    int ky = t / KS_, kx = t - ky * KS_;
    v8s out;
#pragma unroll
    for (int j = 0; j < 8; ++j) {
        int k = kb + j;
        float v = (k < IC) ? src[((oc * IC + k) * KS_ + ky) * KS_ + kx] : 0.f;
        out[j] = (short)f2b(v);
    }
    ((v8s*)ws)[u] = out;
}

// ---------------- conv core: tap-decomposed implicit GEMM on MFMA ----------------
template<int MT, int KF, int TAPS, int KS, int PAD,
         int IN_OFF, int IN_SH, int IN_ROWS, int WS_BASE, int MT_TOT>
__device__ __forceinline__ void conv_core(const uint8_t* smem, const v8s* __restrict__ wsv,
                                          int l, const int* px, const int* py,
                                          v4f (&acc)[MT][3])
{
    const int kgoff = ((l >> 4) << 4);
    for (int t = 0; t < TAPS; ++t) {
        const int ky = t / KS, kx = t - ky * KS;
        const int dx = ky - PAD, dy = kx - PAD;
        v8s af[MT][KF];
#pragma unroll
        for (int m = 0; m < MT; ++m)
#pragma unroll
            for (int kf = 0; kf < KF; ++kf)
                af[m][kf] = wsv[WS_BASE + ((t * KF + kf) * MT_TOT + m) * 64 + l];
#pragma unroll
        for (int i = 0; i < 3; ++i) {
            const int xi = px[i] + dx;
            const int rowp = xi * IN_ROWS + py[i] + dy + PAD;
            int a;
            if (IN_SH == 7) a = ((rowp << 7) | kgoff) ^ ((rowp & 7) << 4);
            else            a = ((rowp << 6) | kgoff) ^ SWZ64(rowp);
            a = ((unsigned)xi < 32u) ? a : kgoff;
            a += IN_OFF;
            const v8s bf0 = *(const v8s*)(smem + a);
#pragma unroll
            for (int m = 0; m < MT; ++m)
                acc[m][i] = __builtin_amdgcn_mfma_f32_16x16x32_bf16(af[m][0], bf0, acc[m][i], 0, 0, 0);
            if (KF == 2) {
                const v8s bf1 = *(const v8s*)(smem + (a ^ 64));
#pragma unroll
                for (int m = 0; m < MT; ++m)
                    acc[m][i] = __builtin_amdgcn_mfma_f32_16x16x32_bf16(af[m][1], bf1, acc[m][i], 0, 0, 0);
            }
        }
    }
}

// ---------------- conv epilogue: bias+relu+bf16 pack, packed b64 stores ----------------
template<int MTOT, int M0, int M1, int OUT_OFF, int OUT_SH, int OUT_ROWS, int OUT_PAD>
__device__ __forceinline__ void conv_epi(uint8_t* smem, const float* __restrict__ bias,
                                         v4f (&acc)[MTOT][3], const int* px, const int* py, int kg)
{
#pragma unroll
    for (int m = M0; m < M1; ++m) {
        const float* bp = bias + m * 16 + kg * 4;
        const float bb0 = bp[0], bb1 = bp[1], bb2 = bp[2], bb3 = bp[3];
#pragma unroll
        for (int i = 0; i < 3; ++i) {
            const float v0 = fmaxf(acc[m][i][0] + bb0, 0.f);
            const float v1 = fmaxf(acc[m][i][1] + bb1, 0.f);
            const float v2 = fmaxf(acc[m][i][2] + bb2, 0.f);
            const float v3 = fmaxf(acc[m][i][3] + bb3, 0.f);
            uint2 pk;
            pk.x = pkbf(v0, v1);
            pk.y = pkbf(v2, v3);
            const int rowp = px[i] * OUT_ROWS + py[i] + OUT_PAD;
            const int coff = (m - M0) * 32 + (kg << 3);
            int a;
            if (OUT_SH == 7) a = ((rowp << 7) | coff) ^ ((rowp & 7) << 4);
            else             a = ((rowp << 6) | coff) ^ SWZ64(rowp);
            *(uint2*)(smem + OUT_OFF + a) = pk;
        }
    }
}

// ---------------- gather one conv2 half via register bitmask (256 threads) ----------------
__device__ __forceinline__ void gather_half(const uint8_t* smem,
                                            const uint32_t* __restrict__ mk,
                                            const int* __restrict__ rpl,
                                            int gr, int gl, float* yreg)
{
    const int pxr = rpl[gr * 2], pyr = rpl[gr * 2 + 1];
    const uint32_t mlo = mk[gr * 2], mhi = mk[gr * 2 + 1];
    float s0=0,s1=0,s2=0,s3=0,s4=0,s5=0,s6=0,s7=0;
#pragma unroll
    for (int cell = 0; cell < 36; ++cell) {
        const uint32_t w = (cell < 32) ? mlo : mhi;
        if ((w >> (cell & 31)) & 1u) {
            const int p = (pxr + cell / 6) * 24 + pyr + (cell % 6);
            const v8s v = *(const v8s*)(smem + X3_OFF +
                (((p << 6) | (gl << 4)) ^ SWZ64(p)));
            s0 += b2f((uint16_t)v[0]);
            s1 += b2f((uint16_t)v[1]);
            s2 += b2f((uint16_t)v[2]);
            s3 += b2f((uint16_t)v[3]);
            s4 += b2f((uint16_t)v[4]);
            s5 += b2f((uint16_t)v[5]);
            s6 += b2f((uint16_t)v[6]);
            s7 += b2f((uint16_t)v[7]);
        }
    }
    yreg[0]=s0; yreg[1]=s1; yreg[2]=s2; yreg[3]=s3;
    yreg[4]=s4; yreg[5]=s5; yreg[6]=s6; yreg[7]=s7;
}

// ---------------- MLP layer (f32), 1024 threads: 16 groups x 4 outputs ----------------
template<bool RELU>
__device__ __forceinline__ void mlp_layer(uint8_t* smem, int inoff, int outoff,
                                          const float* __restrict__ W,
                                          const float* __restrict__ bias, int tid)
{
    const int og = tid >> 6, r = tid & 63;
    const int ogs = __builtin_amdgcn_readfirstlane(og);
    const int swz = (r & 7) << 4;
    float acc[4];
#pragma unroll
    for (int oo = 0; oo < 4; ++oo) acc[oo] = bias[ogs * 4 + oo];
    const float* Wb = W + ogs * 4 * 64;
#pragma unroll
    for (int cg = 0; cg < 16; ++cg) {
        const v4f v = *(const v4f*)(smem + inoff + ((r * 256 + cg * 16) ^ swz));
#pragma unroll
        for (int oo = 0; oo < 4; ++oo) {
            const float* wr = Wb + oo * 64 + cg * 4;
            acc[oo] = fmaf(wr[0], v[0], acc[oo]);
            acc[oo] = fmaf(wr[1], v[1], acc[oo]);
            acc[oo] = fmaf(wr[2], v[2], acc[oo]);
            acc[oo] = fmaf(wr[3], v[3], acc[oo]);
        }
    }
    if (RELU)
#pragma unroll
        for (int oo = 0; oo < 4; ++oo) acc[oo] = fmaxf(acc[oo], 0.f);
    const v4f o0 = {acc[0], acc[1], acc[2], acc[3]};
    *(v4f*)(smem + outoff + ((r * 256 + ogs * 16) ^ swz)) = o0;
}

// ---------------- fused main kernel: one block (16 waves) per sample ----------------
__global__ __launch_bounds__(TPB)
void fused_main(const int* __restrict__ rpos,
                const float* __restrict__ rooms,
                const float* __restrict__ emb,
                const float* __restrict__ b0, const float* __restrict__ b1,
                const float* __restrict__ b2,
                const float* __restrict__ rw0, const float* __restrict__ rb0,
                const float* __restrict__ rw1, const float* __restrict__ rb1,
                const float* __restrict__ rw2, const float* __restrict__ rb2,
                const uint8_t* __restrict__ ws,
                float* __restrict__ out)
{
    __shared__ __align__(16) uint8_t smem[SMEM_BYTES];
    const int tid = threadIdx.x, n = blockIdx.x;
    const int* rp = rpos + n * 128;
    const v8s* wsv = (const v8s*)ws;
    uint32_t* mk  = (uint32_t*)(smem + MK_OFF);
    uint8_t*  ch8 = smem + CH8_OFF;
    int*      rpl = (int*)(smem + RPL_OFF);
    uint32_t* mw  = (uint32_t*)(smem + MW_OFF);
    float*    embl = (float*)(smem + EMB_OFF);

    // ---- P0: stage bitmasks / emb / positions into LDS ----
    embl[tid] = emb[tid];                                   // 64*16 = 1024 floats
    if (tid < 112) mw[tid] = 0;
    if (tid >= 128 && tid < 256) mk[tid - 128] = 0;
    if (tid >= 256 && tid < 384) rpl[tid - 256] = rp[tid - 256];
    __syncthreads();
    if (tid < 64) {                                         // coverage masks
        const int pxr = rpl[2 * tid], pyr = rpl[2 * tid + 1];
        const uint32_t bit = 1u << (tid & 31);
        const int xb = (tid >> 5) * 32, yb = 64 + (tid >> 5) * 24;
#pragma unroll
        for (int i = 0; i < 6; ++i) atomicOr(&mw[xb + pxr + i], bit);
#pragma unroll
        for (int j = 0; j < 6; ++j) atomicOr(&mw[yb + pyr + j], bit);
    }
    for (int q = tid; q < 2304; q += TPB) {                 // room bitmasks (rooms ∈ {0,1})
        const int r = (q * 1821) >> 16;                     // q / 36
        const int cell = q - r * 36;
        const float* base = rooms + r * 324 + cell;
        uint32_t bits = 0;
#pragma unroll
        for (int c = 1; c < 9; ++c)
            bits |= (base[c * 36] != 0.f ? 1u : 0u) << (c - 1);
        ch8[q] = (uint8_t)bits;
        if (base[0] != 0.f) atomicOr(&mk[r * 2 + (cell >> 5)], 1u << (cell & 31));
    }
    __syncthreads();

    // ---- P1: scatter via bitmasks (no global loads in the loop) ----
    if (tid < 768) {
        const int x = (tid * 2731) >> 16;
        const int y = tid - x * 24;
        float a[26];
#pragma unroll
        for (int c = 0; c < 26; ++c) a[c] = 0.f;
        a[9] = 1.f;
        uint32_t mlo = mw[x] & mw[64 + y];
        uint32_t mhi = mw[32 + x] & mw[88 + y];
#pragma unroll 1
        for (int half = 0; half < 2; ++half) {
            uint32_t mm = half ? mhi : mlo;
            const int rb = half ? 32 : 0;
            while (mm) {
                const int r = rb + __builtin_ctz(mm);
                mm &= mm - 1;
                const int cell = (x - rpl[2 * r]) * 6 + (y - rpl[2 * r + 1]);
                const uint32_t w = mk[r * 2 + (cell >> 5)];
                if ((w >> (cell & 31)) & 1u) {
                    a[0] += 1.f;
                    const uint32_t bits = ch8[r * 36 + cell];
#pragma unroll
                    for (int c = 0; c < 8; ++c)
                        a[1 + c] += (float)((bits >> c) & 1u);
                    const float* er = embl + r * 16;
#pragma unroll
                    for (int e = 0; e < 16; ++e) a[10 + e] += er[e];
                }
            }
        }
        const int row = x * 28 + y + 2;
        const int swz = SWZ64(row);
#pragma unroll
        for (int cg = 0; cg < 4; ++cg) {
            float c[8];
#pragma unroll
            for (int j = 0; j < 8; ++j) {
                const int ci = cg * 8 + j;
                c[j] = (ci < 26) ? a[(ci < 26) ? ci : 0] : 0.f;
            }
            uint2 p0, p1;
            p0.x = pkbf(c[0], c[1]); p0.y = pkbf(c[2], c[3]);
            p1.x = pkbf(c[4], c[5]); p1.y = pkbf(c[6], c[7]);
            const int a0 = X0_OFF + (((row << 6) | (cg << 4)) ^ swz);
            *(uint2*)(smem + a0)     = p0;
            *(uint2*)(smem + a0 + 8) = p1;
        }
    } else {
        const int base = (tid - 768) * 2;                   // X0 y-pad rows
#pragma unroll
        for (int k = 0; k < 2; ++k) {
            const int u = base + k;
            const int rowi = u >> 2, slot = u & 3;
            const int x = rowi >> 2, yp = rowi & 3;
            const int row = x * 28 + ((yp < 2) ? yp : yp + 24);
            *(v8s*)(smem + X0_OFF + (((row << 6) | (slot << 4)) ^ SWZ64(row))) =
                (v8s){0,0,0,0,0,0,0,0};
        }
    }
    __syncthreads();

    // per-thread MFMA geometry
    const int l = tid & 63, wv = tid >> 6, kg = l >> 4;
    int px[3], py[3];
#pragma unroll
    for (int i = 0; i < 3; ++i) {
        const int p = (wv + 16 * i) * 16 + (l & 15);
        const int x = (p * 2731) >> 16;
        px[i] = x; py[i] = p - x * 24;
    }

    // ---- P2: conv0 (26->32, 5x5) + X1 pad zero ----
    {
        if (tid < 256) {
            const int rowi = tid >> 2, slot = tid & 3;
            const int x = rowi >> 1;
            const int rowp = x * 26 + ((rowi & 1) ? 25 : 0);
            *(v8s*)(smem + X1_OFF + (((rowp << 6) | (slot << 4)) ^ SWZ64(rowp))) =
                (v8s){0,0,0,0,0,0,0,0};
        }
        v4f acc[2][3];
#pragma unroll
        for (int m = 0; m < 2; ++m)
#pragma unroll
            for (int i = 0; i < 3; ++i) acc[m][i] = (v4f){0.f,0.f,0.f,0.f};
        conv_core<2,1,25,5,2, X0_OFF,6,28, WS0_U,2>(smem, wsv, l, px, py, acc);
        conv_epi<2,0,2, X1_OFF,6,26,1>(smem, b0, acc, px, py, kg);
    }
    __syncthreads();

    // ---- P3: conv1 (32->64, 3x3) + X2 pad zero ----
    {
        if (tid < 512) {
            const int rowi = tid >> 3, slot = tid & 7;
            const int x = rowi >> 1;
            const int rowp = x * 26 + ((rowi & 1) ? 25 : 0);
            *(v8s*)(smem + X2_OFF + (((rowp << 7) | (slot << 4)) ^ ((rowp & 7) << 4))) =
                (v8s){0,0,0,0,0,0,0,0};
        }
        v4f acc[4][3];
#pragma unroll
        for (int m = 0; m < 4; ++m)
#pragma unroll
            for (int i = 0; i < 3; ++i) acc[m][i] = (v4f){0.f,0.f,0.f,0.f};
        conv_core<4,1,9,3,1, X1_OFF,6,26, WS1_U,4>(smem, wsv, l, px, py, acc);
        conv_epi<4,0,4, X2_OFF,7,26,1>(smem, b1, acc, px, py, kg);
    }
    __syncthreads();

    // ---- P4: conv2 (64->64, 3x3) single K-sweep, two-stage epilogue + bit-gather ----
    float yregA[8], yregB[8];
    {
        v4f acc[4][3];
#pragma unroll
        for (int m = 0; m < 4; ++m)
#pragma unroll
            for (int i = 0; i < 3; ++i) acc[m][i] = (v4f){0.f,0.f,0.f,0.f};
        conv_core<4,2,9,3,1, X2_OFF,7,26, WS2_U,4>(smem, wsv, l, px, py, acc);
        conv_epi<4,0,2, X3_OFF,6,24,0>(smem, b2, acc, px, py, kg);   // X3 disjoint from X2
        __syncthreads();
        if (tid < 256) gather_half(smem, mk, rpl, tid >> 2, tid & 3, yregA);
        __syncthreads();
        conv_epi<4,2,4, X3_OFF,6,24,0>(smem, b2, acc, px, py, kg);
        __syncthreads();
        if (tid < 256) gather_half(smem, mk, rpl, tid >> 2, tid & 3, yregB);
        __syncthreads();
    }

    // ---- P5: assemble Y f32 [r][c] (swizzled rows) ----
    if (tid < 256) {
        const int gr = tid >> 2, gl = tid & 3;
        const int swz = (gr & 7) << 4;
        const int baseA = gr * 256 + gl * 32;
        const int baseB = baseA + 128;
        *(v4f*)(smem + YA_OFF + (baseA ^ swz))        = (v4f){yregA[0], yregA[1], yregA[2], yregA[3]};
        *(v4f*)(smem + YA_OFF + ((baseA + 16) ^ swz)) = (v4f){yregA[4], yregA[5], yregA[6], yregA[7]};
        *(v4f*)(smem + YA_OFF + (baseB ^ swz))        = (v4f){yregB[0], yregB[1], yregB[2], yregB[3]};
        *(v4f*)(smem + YA_OFF + ((baseB + 16) ^ swz)) = (v4f){yregB[4], yregB[5], yregB[6], yregB[7]};
    }
    __syncthreads();

    // ---- P6: 3-layer room MLP (f32), all in LDS ----
    mlp_layer<true >(smem, YA_OFF, YB_OFF, rw0, rb0, tid);
    __syncthreads();
    mlp_layer<true >(smem, YB_OFF, YA_OFF, rw1, rb1, tid);
    __syncthreads();
    mlp_layer<false>(smem, YA_OFF, YB_OFF, rw2, rb2, tid);
    __syncthreads();

    // ---- P7: coalesced output store ----
    {
        const int r = tid >> 4, cg = tid & 15;
        const int swz = (r & 7) << 4;
        const v4f v = *(const v4f*)(smem + YB_OFF + ((r * 256 + cg * 16) ^ swz));
        *(v4f*)(out + n * 4096 + r * 64 + cg * 4) = v;
    }
}

extern "C" void kernel_launch(void* const* d_in, const int* in_sizes, int n_in,
                              void* d_out, int out_size, void* d_ws, size_t ws_size,
                              hipStream_t stream) {
    const int*   rpos  = (const int*)  d_in[0];
    const float* rooms = (const float*)d_in[1];
    const float* emb   = (const float*)d_in[2];
    const float* w0    = (const float*)d_in[3];
    const float* b0    = (const float*)d_in[4];
    const float* w1    = (const float*)d_in[5];
    const float* b1    = (const float*)d_in[6];
    const float* w2    = (const float*)d_in[7];
    const float* b2    = (const float*)d_in[8];
    const float* rw0   = (const float*)d_in[9];
    const float* rb0   = (const float*)d_in[10];
    const float* rw1   = (const float*)d_in[11];
    const float* rb1   = (const float*)d_in[12];
    const float* rw2   = (const float*)d_in[13];
    const float* rb2   = (const float*)d_in[14];
    float* out = (float*)d_out;
    uint8_t* ws = (uint8_t*)d_ws;

    const int n = in_sizes[0] / 128;   // samples (512)
    hipLaunchKernelGGL(prep_weights, dim3((WS_UNITS + 255) / 256), dim3(256), 0, stream,
                       w0, w1, w2, ws);
    hipLaunchKernelGGL(fused_main, dim3(n), dim3(TPB), 0, stream,
                       rpos, rooms, emb, b0, b1, b2,
                       rw0, rb0, rw1, rb1, rw2, rb2, ws, out);
}

// Round 18
// 104.264 us; speedup vs baseline: 1.4293x; 1.0468x over previous
//
#include <hip/hip_runtime.h>
#include <hip/hip_bf16.h>
#include <stdint.h>

typedef short v8s __attribute__((ext_vector_type(8)));
typedef float v4f __attribute__((ext_vector_type(4)));

#define TPB 1024

// ---- LDS layout (bytes) ----
// X0 [896][64B] swz(row>>1)&3 @0        57,344   (P1 scatter out, P2 in)
// X1 [832][64B] swz(row>>1)&3 @106,496  53,248   (P2 out, P3 in)
// X2 [832][128B] swz&7        @0       106,496   (P3 out, P4 in; X0 dead)
// X3A [768][64B] oc0-31       @106,496  49,152   (P4 epi half0; X1 dead)
// X3B [768][64B] oc32-63      @0        49,152   (P4 epi half1; X2 dead, barrier-guarded)
// Ya/Yb f32 [64][64]          @49,152/@65,536    (gather+MLP; free window)
// EMB f32[64][16]             @57,344    4,096   (P1 only; overlaps Ya region, dead by gather)
// MK  u32[128] room masks     @159,744     512   (persistent)
// CH8 u8[64][36] ch1-8 bits   @160,256   2,304   (persistent)
// RPL int[128] positions      @162,560     512   (persistent)
// MW  u32[112] coverage       @163,072     448   (P1 only)
#define X0_OFF 0
#define X1_OFF 106496
#define X2_OFF 0
#define X3A_OFF 106496
#define X3B_OFF 0
#define YA_OFF 49152
#define YB_OFF 65536
#define EMB_OFF 57344
#define MK_OFF 159744
#define CH8_OFF 160256
#define RPL_OFF 162560
#define MW_OFF 163072
#define SMEM_BYTES 163520

// ws fragment bases (16B units): conv0 50 frags, conv1 36, conv2 72 (x64 lanes)
#define WS0_U 0
#define WS1_U 3200
#define WS2_U 5504
#define WS_UNITS 10112
#define WS_W_BYTES (WS_UNITS * 16)      // 161,792
// sample-independent bitmasks, precomputed in prep_all:
#define MKG_OFF  WS_W_BYTES             // u32[128]  @161,792
#define CH8G_OFF (WS_W_BYTES + 512)     // u8[2304]  @162,304

// 64B-row swizzle: key on (row>>1)&3 -> 8 distinct banks over 8 consecutive rows
#define SWZ64(row) ((((row) >> 1) & 3) << 4)

__device__ __forceinline__ uint16_t f2b(float f) {
    __hip_bfloat16 h = __float2bfloat16(f);
    return *reinterpret_cast<uint16_t*>(&h);
}
__device__ __forceinline__ uint32_t pkbf(float lo, float hi) {
    return (uint32_t)f2b(lo) | ((uint32_t)f2b(hi) << 16);
}
__device__ __forceinline__ float b2f(uint16_t h) {
    return __uint_as_float(((uint32_t)h) << 16);
}

// ---------------- prep: weights (blocks 0-39) + room bitmasks (blocks 40-49) ----------------
__global__ void prep_all(const float* __restrict__ w0,
                         const float* __restrict__ w1,
                         const float* __restrict__ w2,
                         const float* __restrict__ rooms,
                         uint8_t* __restrict__ ws)
{
    const int bid = blockIdx.x, t = threadIdx.x;
    if (bid < 40) {
        int u = bid * 256 + t;
        if (u >= WS_UNITS) return;
        int l = u & 63, fid = u >> 6;
        const float* src; int IC, KS_, tt, kf, m;
        if (fid < 50)      { src = w0; IC = 26; KS_ = 5; tt = fid >> 1; kf = 0; m = fid & 1; }
        else if (fid < 86) { int v = fid - 50; src = w1; IC = 32; KS_ = 3; tt = v >> 2; kf = 0; m = v & 3; }
        else               { int v = fid - 86; src = w2; IC = 64; KS_ = 3; tt = v >> 3; kf = (v >> 2) & 1; m = v & 3; }
        int oc = m * 16 + (l & 15);
        int kb = kf * 32 + ((l >> 4) * 8);
        int ky = tt / KS_, kx = tt - ky * KS_;
        v8s out;
#pragma unroll
        for (int j = 0; j < 8; ++j) {
            int k = kb + j;
            float v = (k < IC) ? src[((oc * IC + k) * KS_ + ky) * KS_ + kx] : 0.f;
            out[j] = (short)f2b(v);
        }
        ((v8s*)ws)[u] = out;
    } else if (bid < 49) {
        const int q = (bid - 40) * 256 + t;              // 0..2303
        const int r = (q * 1821) >> 16;                  // q / 36
        const int cell = q - r * 36;
        const float* base = rooms + r * 324 + cell;
        uint32_t bits = 0;
#pragma unroll
        for (int c = 1; c < 9; ++c)
            bits |= (base[c * 36] != 0.f ? 1u : 0u) << (c - 1);
        ws[CH8G_OFF + q] = (uint8_t)bits;
    } else {
        if (t < 128) {                                   // mask-channel bits
            const int r = t >> 1, h = t & 1;
            const float* rr = rooms + r * 324;
            uint32_t m = 0;
            const int c0 = h * 32, c1 = h ? 36 : 32;
            for (int cell = c0; cell < c1; ++cell)
                if (rr[cell] != 0.f) m |= 1u << (cell - c0);
            ((uint32_t*)(ws + MKG_OFF))[t] = m;
        }
    }
}

// ---------------- conv core: tap-decomposed implicit GEMM on MFMA ----------------
template<int MT, int KF, int TAPS, int KS, int PAD,
         int IN_OFF, int IN_SH, int IN_ROWS, int WS_BASE, int MT_TOT>
__device__ __forceinline__ void conv_core(const uint8_t* smem, const v8s* __restrict__ wsv,
                                          int l, const int* px, const int* py,
                                          v4f (&acc)[MT][3])
{
    const int kgoff = ((l >> 4) << 4);
    for (int t = 0; t < TAPS; ++t) {
        const int ky = t / KS, kx = t - ky * KS;
        const int dx = ky - PAD, dy = kx - PAD;
        v8s af[MT][KF];
#pragma unroll
        for (int m = 0; m < MT; ++m)
#pragma unroll
            for (int kf = 0; kf < KF; ++kf)
                af[m][kf] = wsv[WS_BASE + ((t * KF + kf) * MT_TOT + m) * 64 + l];
#pragma unroll
        for (int i = 0; i < 3; ++i) {
            const int xi = px[i] + dx;
            const int rowp = xi * IN_ROWS + py[i] + dy + PAD;
            int a;
            if (IN_SH == 7) a = ((rowp << 7) | kgoff) ^ ((rowp & 7) << 4);
            else            a = ((rowp << 6) | kgoff) ^ SWZ64(rowp);
            a = ((unsigned)xi < 32u) ? a : kgoff;
            a += IN_OFF;
            const v8s bf0 = *(const v8s*)(smem + a);
#pragma unroll
            for (int m = 0; m < MT; ++m)
                acc[m][i] = __builtin_amdgcn_mfma_f32_16x16x32_bf16(af[m][0], bf0, acc[m][i], 0, 0, 0);
            if (KF == 2) {
                const v8s bf1 = *(const v8s*)(smem + (a ^ 64));
#pragma unroll
                for (int m = 0; m < MT; ++m)
                    acc[m][i] = __builtin_amdgcn_mfma_f32_16x16x32_bf16(af[m][1], bf1, acc[m][i], 0, 0, 0);
            }
        }
    }
}

// ---------------- conv epilogue: bias+relu+bf16 pack, packed b64 stores ----------------
template<int MTOT, int M0, int M1, int OUT_OFF, int OUT_SH, int OUT_ROWS, int OUT_PAD>
__device__ __forceinline__ void conv_epi(uint8_t* smem, const float* __restrict__ bias,
                                         v4f (&acc)[MTOT][3], const int* px, const int* py, int kg)
{
#pragma unroll
    for (int m = M0; m < M1; ++m) {
        const float* bp = bias + m * 16 + kg * 4;
        const float bb0 = bp[0], bb1 = bp[1], bb2 = bp[2], bb3 = bp[3];
#pragma unroll
        for (int i = 0; i < 3; ++i) {
            const float v0 = fmaxf(acc[m][i][0] + bb0, 0.f);
            const float v1 = fmaxf(acc[m][i][1] + bb1, 0.f);
            const float v2 = fmaxf(acc[m][i][2] + bb2, 0.f);
            const float v3 = fmaxf(acc[m][i][3] + bb3, 0.f);
            uint2 pk;
            pk.x = pkbf(v0, v1);
            pk.y = pkbf(v2, v3);
            const int rowp = px[i] * OUT_ROWS + py[i] + OUT_PAD;
            const int coff = (m - M0) * 32 + (kg << 3);
            int a;
            if (OUT_SH == 7) a = ((rowp << 7) | coff) ^ ((rowp & 7) << 4);
            else             a = ((rowp << 6) | coff) ^ SWZ64(rowp);
            *(uint2*)(smem + OUT_OFF + a) = pk;
        }
    }
}

// ---------------- MLP layer (f32), 1024 threads: 16 groups x 4 outputs ----------------
template<bool RELU>
__device__ __forceinline__ void mlp_layer(uint8_t* smem, int inoff, int outoff,
                                          const float* __restrict__ W,
                                          const float* __restrict__ bias, int tid)
{
    const int og = tid >> 6, r = tid & 63;
    const int ogs = __builtin_amdgcn_readfirstlane(og);
    const int swz = (r & 7) << 4;
    float acc[4];
#pragma unroll
    for (int oo = 0; oo < 4; ++oo) acc[oo] = bias[ogs * 4 + oo];
    const float* Wb = W + ogs * 4 * 64;
#pragma unroll
    for (int cg = 0; cg < 16; ++cg) {
        const v4f v = *(const v4f*)(smem + inoff + ((r * 256 + cg * 16) ^ swz));
#pragma unroll
        for (int oo = 0; oo < 4; ++oo) {
            const float* wr = Wb + oo * 64 + cg * 4;
            acc[oo] = fmaf(wr[0], v[0], acc[oo]);
            acc[oo] = fmaf(wr[1], v[1], acc[oo]);
            acc[oo] = fmaf(wr[2], v[2], acc[oo]);
            acc[oo] = fmaf(wr[3], v[3], acc[oo]);
        }
    }
    if (RELU)
#pragma unroll
        for (int oo = 0; oo < 4; ++oo) acc[oo] = fmaxf(acc[oo], 0.f);
    const v4f o0 = {acc[0], acc[1], acc[2], acc[3]};
    *(v4f*)(smem + outoff + ((r * 256 + ogs * 16) ^ swz)) = o0;
}

// ---------------- fused main kernel: one block (16 waves) per sample ----------------
__global__ __launch_bounds__(TPB)
void fused_main(const int* __restrict__ rpos,
                const float* __restrict__ rooms,
                const float* __restrict__ emb,
                const float* __restrict__ b0, const float* __restrict__ b1,
                const float* __restrict__ b2,
                const float* __restrict__ rw0, const float* __restrict__ rb0,
                const float* __restrict__ rw1, const float* __restrict__ rb1,
                const float* __restrict__ rw2, const float* __restrict__ rb2,
                const uint8_t* __restrict__ ws,
                float* __restrict__ out)
{
    __shared__ __align__(16) uint8_t smem[SMEM_BYTES];
    const int tid = threadIdx.x, n = blockIdx.x;
    const int* rp = rpos + n * 128;
    const v8s* wsv = (const v8s*)ws;
    uint32_t* mk  = (uint32_t*)(smem + MK_OFF);
    uint8_t*  ch8 = smem + CH8_OFF;
    int*      rpl = (int*)(smem + RPL_OFF);
    uint32_t* mw  = (uint32_t*)(smem + MW_OFF);
    float*    embl = (float*)(smem + EMB_OFF);

    // ---- P0: stage emb/positions + COPY precomputed bitmasks ----
    embl[tid] = emb[tid];                                   // 64*16 = 1024 floats
    if (tid < 112) mw[tid] = 0;
    if (tid >= 128 && tid < 256) mk[tid - 128] = ((const uint32_t*)(ws + MKG_OFF))[tid - 128];
    if (tid >= 256 && tid < 384) rpl[tid - 256] = rp[tid - 256];
    if (tid >= 384 && tid < 960) ((uint32_t*)ch8)[tid - 384] =
        ((const uint32_t*)(ws + CH8G_OFF))[tid - 384];      // 576 u32 = 2,304 B
    __syncthreads();
    if (tid < 64) {                                         // coverage masks
        const int pxr = rpl[2 * tid], pyr = rpl[2 * tid + 1];
        const uint32_t bit = 1u << (tid & 31);
        const int xb = (tid >> 5) * 32, yb = 64 + (tid >> 5) * 24;
#pragma unroll
        for (int i = 0; i < 6; ++i) atomicOr(&mw[xb + pxr + i], bit);
#pragma unroll
        for (int j = 0; j < 6; ++j) atomicOr(&mw[yb + pyr + j], bit);
    }
    __syncthreads();

    // ---- P1: scatter via bitmasks (no global loads in the loop) ----
    if (tid < 768) {
        const int x = (tid * 2731) >> 16;
        const int y = tid - x * 24;
        float a[26];
#pragma unroll
        for (int c = 0; c < 26; ++c) a[c] = 0.f;
        a[9] = 1.f;
        uint32_t mlo = mw[x] & mw[64 + y];
        uint32_t mhi = mw[32 + x] & mw[88 + y];
#pragma unroll 1
        for (int half = 0; half < 2; ++half) {
            uint32_t mm = half ? mhi : mlo;
            const int rb = half ? 32 : 0;
            while (mm) {
                const int r = rb + __builtin_ctz(mm);
                mm &= mm - 1;
                const int cell = (x - rpl[2 * r]) * 6 + (y - rpl[2 * r + 1]);
                const uint32_t w = mk[r * 2 + (cell >> 5)];
                if ((w >> (cell & 31)) & 1u) {
                    a[0] += 1.f;
                    const uint32_t bits = ch8[r * 36 + cell];
#pragma unroll
                    for (int c = 0; c < 8; ++c)
                        a[1 + c] += (float)((bits >> c) & 1u);
                    const float* er = embl + r * 16;
#pragma unroll
                    for (int e = 0; e < 16; ++e) a[10 + e] += er[e];
                }
            }
        }
        const int row = x * 28 + y + 2;
        const int swz = SWZ64(row);
#pragma unroll
        for (int cg = 0; cg < 4; ++cg) {
            float c[8];
#pragma unroll
            for (int j = 0; j < 8; ++j) {
                const int ci = cg * 8 + j;
                c[j] = (ci < 26) ? a[(ci < 26) ? ci : 0] : 0.f;
            }
            uint2 p0, p1;
            p0.x = pkbf(c[0], c[1]); p0.y = pkbf(c[2], c[3]);
            p1.x = pkbf(c[4], c[5]); p1.y = pkbf(c[6], c[7]);
            const int a0 = X0_OFF + (((row << 6) | (cg << 4)) ^ swz);
            *(uint2*)(smem + a0)     = p0;
            *(uint2*)(smem + a0 + 8) = p1;
        }
    } else {
        const int base = (tid - 768) * 2;                   // X0 y-pad rows
#pragma unroll
        for (int k = 0; k < 2; ++k) {
            const int u = base + k;
            const int rowi = u >> 2, slot = u & 3;
            const int x = rowi >> 2, yp = rowi & 3;
            const int row = x * 28 + ((yp < 2) ? yp : yp + 24);
            *(v8s*)(smem + X0_OFF + (((row << 6) | (slot << 4)) ^ SWZ64(row))) =
                (v8s){0,0,0,0,0,0,0,0};
        }
    }
    __syncthreads();

    // per-thread MFMA geometry
    const int l = tid & 63, wv = tid >> 6, kg = l >> 4;
    int px[3], py[3];
#pragma unroll
    for (int i = 0; i < 3; ++i) {
        const int p = (wv + 16 * i) * 16 + (l & 15);
        const int x = (p * 2731) >> 16;
        px[i] = x; py[i] = p - x * 24;
    }

    // ---- P2: conv0 (26->32, 5x5) + X1 pad zero ----
    {
        if (tid < 256) {
            const int rowi = tid >> 2, slot = tid & 3;
            const int x = rowi >> 1;
            const int rowp = x * 26 + ((rowi & 1) ? 25 : 0);
            *(v8s*)(smem + X1_OFF + (((rowp << 6) | (slot << 4)) ^ SWZ64(rowp))) =
                (v8s){0,0,0,0,0,0,0,0};
        }
        v4f acc[2][3];
#pragma unroll
        for (int m = 0; m < 2; ++m)
#pragma unroll
            for (int i = 0; i < 3; ++i) acc[m][i] = (v4f){0.f,0.f,0.f,0.f};
        conv_core<2,1,25,5,2, X0_OFF,6,28, WS0_U,2>(smem, wsv, l, px, py, acc);
        conv_epi<2,0,2, X1_OFF,6,26,1>(smem, b0, acc, px, py, kg);
    }
    __syncthreads();

    // ---- P3: conv1 (32->64, 3x3) + X2 pad zero ----
    {
        if (tid < 512) {
            const int rowi = tid >> 3, slot = tid & 7;
            const int x = rowi >> 1;
            const int rowp = x * 26 + ((rowi & 1) ? 25 : 0);
            *(v8s*)(smem + X2_OFF + (((rowp << 7) | (slot << 4)) ^ ((rowp & 7) << 4))) =
                (v8s){0,0,0,0,0,0,0,0};
        }
        v4f acc[4][3];
#pragma unroll
        for (int m = 0; m < 4; ++m)
#pragma unroll
            for (int i = 0; i < 3; ++i) acc[m][i] = (v4f){0.f,0.f,0.f,0.f};
        conv_core<4,1,9,3,1, X1_OFF,6,26, WS1_U,4>(smem, wsv, l, px, py, acc);
        conv_epi<4,0,4, X2_OFF,7,26,1>(smem, b1, acc, px, py, kg);
    }
    __syncthreads();

    // ---- P4: conv2 (64->64, 3x3) single K-sweep; split-region epilogue; ONE gather ----
    {
        v4f acc[4][3];
#pragma unroll
        for (int m = 0; m < 4; ++m)
#pragma unroll
            for (int i = 0; i < 3; ++i) acc[m][i] = (v4f){0.f,0.f,0.f,0.f};
        conv_core<4,2,9,3,1, X2_OFF,7,26, WS2_U,4>(smem, wsv, l, px, py, acc);
        conv_epi<4,0,2, X3A_OFF,6,24,0>(smem, b2, acc, px, py, kg);  // half0: X1-dead region
        __syncthreads();                                             // drain X2 reads
        conv_epi<4,2,4, X3B_OFF,6,24,0>(smem, b2, acc, px, py, kg);  // half1: X2 region
        __syncthreads();
    }
    // single gather: 512 threads, thread (gr, gg) -> 8 channels, straight to Ya in LDS
    if (tid < 512) {
        const int gr = tid >> 3, gg = tid & 7;
        const int gl = gg & 3;
        const int roff = (gg < 4) ? X3A_OFF : X3B_OFF;
        const int pxr = rpl[gr * 2], pyr = rpl[gr * 2 + 1];
        const uint32_t mlo = mk[gr * 2], mhi = mk[gr * 2 + 1];
        float s0=0,s1=0,s2=0,s3=0,s4=0,s5=0,s6=0,s7=0;
#pragma unroll
        for (int cell = 0; cell < 36; ++cell) {
            const uint32_t w = (cell < 32) ? mlo : mhi;
            if ((w >> (cell & 31)) & 1u) {
                const int p = (pxr + cell / 6) * 24 + pyr + (cell % 6);
                const v8s v = *(const v8s*)(smem + roff +
                    (((p << 6) | (gl << 4)) ^ SWZ64(p)));
                s0 += b2f((uint16_t)v[0]);
                s1 += b2f((uint16_t)v[1]);
                s2 += b2f((uint16_t)v[2]);
                s3 += b2f((uint16_t)v[3]);
                s4 += b2f((uint16_t)v[4]);
                s5 += b2f((uint16_t)v[5]);
                s6 += b2f((uint16_t)v[6]);
                s7 += b2f((uint16_t)v[7]);
            }
        }
        const int base = gr * 256 + gl * 32 + (gg >> 2) * 128;
        const int swz = (gr & 7) << 4;
        *(v4f*)(smem + YA_OFF + (base ^ swz))        = (v4f){s0, s1, s2, s3};
        *(v4f*)(smem + YA_OFF + ((base + 16) ^ swz)) = (v4f){s4, s5, s6, s7};
    }
    __syncthreads();

    // ---- P6: 3-layer room MLP (f32), all in LDS ----
    mlp_layer<true >(smem, YA_OFF, YB_OFF, rw0, rb0, tid);
    __syncthreads();
    mlp_layer<true >(smem, YB_OFF, YA_OFF, rw1, rb1, tid);
    __syncthreads();
    mlp_layer<false>(smem, YA_OFF, YB_OFF, rw2, rb2, tid);
    __syncthreads();

    // ---- P7: coalesced output store ----
    {
        const int r = tid >> 4, cg = tid & 15;
        const int swz = (r & 7) << 4;
        const v4f v = *(const v4f*)(smem + YB_OFF + ((r * 256 + cg * 16) ^ swz));
        *(v4f*)(out + n * 4096 + r * 64 + cg * 4) = v;
    }
}

extern "C" void kernel_launch(void* const* d_in, const int* in_sizes, int n_in,
                              void* d_out, int out_size, void* d_ws, size_t ws_size,
                              hipStream_t stream) {
    const int*   rpos  = (const int*)  d_in[0];
    const float* rooms = (const float*)d_in[1];
    const float* emb   = (const float*)d_in[2];
    const float* w0    = (const float*)d_in[3];
    const float* b0    = (const float*)d_in[4];
    const float* w1    = (const float*)d_in[5];
    const float* b1    = (const float*)d_in[6];
    const float* w2    = (const float*)d_in[7];
    const float* b2    = (const float*)d_in[8];
    const float* rw0   = (const float*)d_in[9];
    const float* rb0   = (const float*)d_in[10];
    const float* rw1   = (const float*)d_in[11];
    const float* rb1   = (const float*)d_in[12];
    const float* rw2   = (const float*)d_in[13];
    const float* rb2   = (const float*)d_in[14];
    float* out = (float*)d_out;
    uint8_t* ws = (uint8_t*)d_ws;

    const int n = in_sizes[0] / 128;   // samples (512)
    hipLaunchKernelGGL(prep_all, dim3(50), dim3(256), 0, stream,
                       w0, w1, w2, rooms, ws);
    hipLaunchKernelGGL(fused_main, dim3(n), dim3(TPB), 0, stream,
                       rpos, rooms, emb, b0, b1, b2,
                       rw0, rb0, rw1, rb1, rw2, rb2, ws, out);
}

// Round 19
// 104.227 us; speedup vs baseline: 1.4298x; 1.0004x over previous
//
#include <hip/hip_runtime.h>
#include <hip/hip_bf16.h>
#include <stdint.h>

typedef short v8s __attribute__((ext_vector_type(8)));
typedef float v4f __attribute__((ext_vector_type(4)));

#define TPB 1024

// ---- LDS layout (bytes) ----
// X0 [896][64B] swz(row>>1)&3 @0        57,344   (P1 scatter out, P2 in)
// X1 [832][64B] swz(row>>1)&3 @106,496  53,248   (P2 out, P3 in)
// X2 [832][128B] swz&7        @0       106,496   (P3 out, P4 in; X0 dead)
// X3A [768][64B] oc0-31       @106,496  49,152   (P4 epi half0; X1 dead)
// X3B [768][64B] oc32-63      @0        49,152   (P4 epi half1; X2 dead, barrier-guarded)
// Ya/Yb f32 [64][64]          @49,152/@65,536    (gather+MLP; free window)
// EMB f32[64][17] stride-17   @57,344    4,352   (P1 only; inside Ya window, dead by gather)
// MKL u32[64] / MKH u32[64]   @159,744/@160,000  (persistent, stride-4B: bank=r%32)
// CH8 u8[64][36] ch1-8 bits   @160,256   2,304   (persistent)
// RPL int[64][3] stride-3     @162,560     768   (persistent)
// MW  u32[112] coverage       @163,328     448   (P1 only)
#define X0_OFF 0
#define X1_OFF 106496
#define X2_OFF 0
#define X3A_OFF 106496
#define X3B_OFF 0
#define YA_OFF 49152
#define YB_OFF 65536
#define EMB_OFF 57344
#define MKL_OFF 159744
#define MKH_OFF 160000
#define CH8_OFF 160256
#define RPL_OFF 162560
#define MW_OFF 163328
#define SMEM_BYTES 163776

// ws fragment bases (16B units): conv0 50 frags, conv1 36, conv2 72 (x64 lanes)
#define WS0_U 0
#define WS1_U 3200
#define WS2_U 5504
#define WS_UNITS 10112
#define WS_W_BYTES (WS_UNITS * 16)      // 161,792
// sample-independent bitmasks, precomputed in prep_all:
#define MKG_OFF  WS_W_BYTES             // u32[128]  @161,792
#define CH8G_OFF (WS_W_BYTES + 512)     // u8[2304]  @162,304

// 64B-row swizzle: key on (row>>1)&3 -> 8 distinct banks over 8 consecutive rows
#define SWZ64(row) ((((row) >> 1) & 3) << 4)

__device__ __forceinline__ uint16_t f2b(float f) {
    __hip_bfloat16 h = __float2bfloat16(f);
    return *reinterpret_cast<uint16_t*>(&h);
}
__device__ __forceinline__ uint32_t pkbf(float lo, float hi) {
    return (uint32_t)f2b(lo) | ((uint32_t)f2b(hi) << 16);
}
__device__ __forceinline__ float b2f(uint16_t h) {
    return __uint_as_float(((uint32_t)h) << 16);
}

// ---------------- prep: weights (blocks 0-39) + room bitmasks (blocks 40-49) ----------------
__global__ void prep_all(const float* __restrict__ w0,
                         const float* __restrict__ w1,
                         const float* __restrict__ w2,
                         const float* __restrict__ rooms,
                         uint8_t* __restrict__ ws)
{
    const int bid = blockIdx.x, t = threadIdx.x;
    if (bid < 40) {
        int u = bid * 256 + t;
        if (u >= WS_UNITS) return;
        int l = u & 63, fid = u >> 6;
        const float* src; int IC, KS_, tt, kf, m;
        if (fid < 50)      { src = w0; IC = 26; KS_ = 5; tt = fid >> 1; kf = 0; m = fid & 1; }
        else if (fid < 86) { int v = fid - 50; src = w1; IC = 32; KS_ = 3; tt = v >> 2; kf = 0; m = v & 3; }
        else               { int v = fid - 86; src = w2; IC = 64; KS_ = 3; tt = v >> 3; kf = (v >> 2) & 1; m = v & 3; }
        int oc = m * 16 + (l & 15);
        int kb = kf * 32 + ((l >> 4) * 8);
        int ky = tt / KS_, kx = tt - ky * KS_;
        v8s out;
#pragma unroll
        for (int j = 0; j < 8; ++j) {
            int k = kb + j;
            float v = (k < IC) ? src[((oc * IC + k) * KS_ + ky) * KS_ + kx] : 0.f;
            out[j] = (short)f2b(v);
        }
        ((v8s*)ws)[u] = out;
    } else if (bid < 49) {
        const int q = (bid - 40) * 256 + t;              // 0..2303
        const int r = (q * 1821) >> 16;                  // q / 36
        const int cell = q - r * 36;
        const float* base = rooms + r * 324 + cell;
        uint32_t bits = 0;
#pragma unroll
        for (int c = 1; c < 9; ++c)
            bits |= (base[c * 36] != 0.f ? 1u : 0u) << (c - 1);
        ws[CH8G_OFF + q] = (uint8_t)bits;
    } else {
        if (t < 128) {                                   // mask-channel bits
            const int r = t >> 1, h = t & 1;
            const float* rr = rooms + r * 324;
            uint32_t m = 0;
            const int c0 = h * 32, c1 = h ? 36 : 32;
            for (int cell = c0; cell < c1; ++cell)
                if (rr[cell] != 0.f) m |= 1u << (cell - c0);
            ((uint32_t*)(ws + MKG_OFF))[t] = m;
        }
    }
}

// ---------------- conv core: tap-decomposed implicit GEMM on MFMA ----------------
template<int MT, int KF, int TAPS, int KS, int PAD,
         int IN_OFF, int IN_SH, int IN_ROWS, int WS_BASE, int MT_TOT>
__device__ __forceinline__ void conv_core(const uint8_t* smem, const v8s* __restrict__ wsv,
                                          int l, const int* px, const int* py,
                                          v4f (&acc)[MT][3])
{
    const int kgoff = ((l >> 4) << 4);
    for (int t = 0; t < TAPS; ++t) {
        const int ky = t / KS, kx = t - ky * KS;
        const int dx = ky - PAD, dy = kx - PAD;
        v8s af[MT][KF];
#pragma unroll
        for (int m = 0; m < MT; ++m)
#pragma unroll
            for (int kf = 0; kf < KF; ++kf)
                af[m][kf] = wsv[WS_BASE + ((t * KF + kf) * MT_TOT + m) * 64 + l];
#pragma unroll
        for (int i = 0; i < 3; ++i) {
            const int xi = px[i] + dx;
            const int rowp = xi * IN_ROWS + py[i] + dy + PAD;
            int a;
            if (IN_SH == 7) a = ((rowp << 7) | kgoff) ^ ((rowp & 7) << 4);
            else            a = ((rowp << 6) | kgoff) ^ SWZ64(rowp);
            a = ((unsigned)xi < 32u) ? a : kgoff;
            a += IN_OFF;
            const v8s bf0 = *(const v8s*)(smem + a);
#pragma unroll
            for (int m = 0; m < MT; ++m)
                acc[m][i] = __builtin_amdgcn_mfma_f32_16x16x32_bf16(af[m][0], bf0, acc[m][i], 0, 0, 0);
            if (KF == 2) {
                const v8s bf1 = *(const v8s*)(smem + (a ^ 64));
#pragma unroll
                for (int m = 0; m < MT; ++m)
                    acc[m][i] = __builtin_amdgcn_mfma_f32_16x16x32_bf16(af[m][1], bf1, acc[m][i], 0, 0, 0);
            }
        }
    }
}

// ---------------- conv epilogue: bias+relu+bf16 pack, packed b64 stores ----------------
template<int MTOT, int M0, int M1, int OUT_OFF, int OUT_SH, int OUT_ROWS, int OUT_PAD>
__device__ __forceinline__ void conv_epi(uint8_t* smem, const float* __restrict__ bias,
                                         v4f (&acc)[MTOT][3], const int* px, const int* py, int kg)
{
#pragma unroll
    for (int m = M0; m < M1; ++m) {
        const float* bp = bias + m * 16 + kg * 4;
        const float bb0 = bp[0], bb1 = bp[1], bb2 = bp[2], bb3 = bp[3];
#pragma unroll
        for (int i = 0; i < 3; ++i) {
            const float v0 = fmaxf(acc[m][i][0] + bb0, 0.f);
            const float v1 = fmaxf(acc[m][i][1] + bb1, 0.f);
            const float v2 = fmaxf(acc[m][i][2] + bb2, 0.f);
            const float v3 = fmaxf(acc[m][i][3] + bb3, 0.f);
            uint2 pk;
            pk.x = pkbf(v0, v1);
            pk.y = pkbf(v2, v3);
            const int rowp = px[i] * OUT_ROWS + py[i] + OUT_PAD;
            const int coff = (m - M0) * 32 + (kg << 3);
            int a;
            if (OUT_SH == 7) a = ((rowp << 7) | coff) ^ ((rowp & 7) << 4);
            else             a = ((rowp << 6) | coff) ^ SWZ64(rowp);
            *(uint2*)(smem + OUT_OFF + a) = pk;
        }
    }
}

// ---------------- MLP layer (f32), 1024 threads: 16 groups x 4 outputs ----------------
template<bool RELU>
__device__ __forceinline__ void mlp_layer(uint8_t* smem, int inoff, int outoff,
                                          const float* __restrict__ W,
                                          const float* __restrict__ bias, int tid)
{
    const int og = tid >> 6, r = tid & 63;
    const int ogs = __builtin_amdgcn_readfirstlane(og);
    const int swz = (r & 7) << 4;
    float acc[4];
#pragma unroll
    for (int oo = 0; oo < 4; ++oo) acc[oo] = bias[ogs * 4 + oo];
    const float* Wb = W + ogs * 4 * 64;
#pragma unroll
    for (int cg = 0; cg < 16; ++cg) {
        const v4f v = *(const v4f*)(smem + inoff + ((r * 256 + cg * 16) ^ swz));
#pragma unroll
        for (int oo = 0; oo < 4; ++oo) {
            const float* wr = Wb + oo * 64 + cg * 4;
            acc[oo] = fmaf(wr[0], v[0], acc[oo]);
            acc[oo] = fmaf(wr[1], v[1], acc[oo]);
            acc[oo] = fmaf(wr[2], v[2], acc[oo]);
            acc[oo] = fmaf(wr[3], v[3], acc[oo]);
        }
    }
    if (RELU)
#pragma unroll
        for (int oo = 0; oo < 4; ++oo) acc[oo] = fmaxf(acc[oo], 0.f);
    const v4f o0 = {acc[0], acc[1], acc[2], acc[3]};
    *(v4f*)(smem + outoff + ((r * 256 + ogs * 16) ^ swz)) = o0;
}

// ---------------- fused main kernel: one block (16 waves) per sample ----------------
__global__ __launch_bounds__(TPB)
void fused_main(const int* __restrict__ rpos,
                const float* __restrict__ rooms,
                const float* __restrict__ emb,
                const float* __restrict__ b0, const float* __restrict__ b1,
                const float* __restrict__ b2,
                const float* __restrict__ rw0, const float* __restrict__ rb0,
                const float* __restrict__ rw1, const float* __restrict__ rb1,
                const float* __restrict__ rw2, const float* __restrict__ rb2,
                const uint8_t* __restrict__ ws,
                float* __restrict__ out)
{
    __shared__ __align__(16) uint8_t smem[SMEM_BYTES];
    const int tid = threadIdx.x, n = blockIdx.x;
    const int* rp = rpos + n * 128;
    const v8s* wsv = (const v8s*)ws;
    uint32_t* mkl = (uint32_t*)(smem + MKL_OFF);
    uint32_t* mkh = (uint32_t*)(smem + MKH_OFF);
    uint8_t*  ch8 = smem + CH8_OFF;
    int*      rpl = (int*)(smem + RPL_OFF);          // stride-3 per room
    uint32_t* mw  = (uint32_t*)(smem + MW_OFF);
    float*    embl = (float*)(smem + EMB_OFF);       // stride-17 per room

    // ---- P0: stage emb/positions + COPY precomputed bitmasks (conflict-free strides) ----
    {
        const int r = tid >> 4, e = tid & 15;        // 64 x 16
        embl[r * 17 + e] = emb[tid];
    }
    if (tid < 112) mw[tid] = 0;
    if (tid >= 128 && tid < 192) mkl[tid - 128] = ((const uint32_t*)(ws + MKG_OFF))[(tid - 128) * 2];
    if (tid >= 192 && tid < 256) mkh[tid - 192] = ((const uint32_t*)(ws + MKG_OFF))[(tid - 192) * 2 + 1];
    if (tid >= 256 && tid < 384) {
        const int idx = tid - 256, r = idx >> 1, c = idx & 1;
        rpl[r * 3 + c] = rp[idx];
    }
    if (tid >= 384 && tid < 960) ((uint32_t*)ch8)[tid - 384] =
        ((const uint32_t*)(ws + CH8G_OFF))[tid - 384];      // 576 u32 = 2,304 B
    __syncthreads();
    if (tid < 64) {                                         // coverage masks
        const int pxr = rpl[3 * tid], pyr = rpl[3 * tid + 1];
        const uint32_t bit = 1u << (tid & 31);
        const int xb = (tid >> 5) * 32, yb = 64 + (tid >> 5) * 24;
#pragma unroll
        for (int i = 0; i < 6; ++i) atomicOr(&mw[xb + pxr + i], bit);
#pragma unroll
        for (int j = 0; j < 6; ++j) atomicOr(&mw[yb + pyr + j], bit);
    }
    __syncthreads();

    // ---- P1: scatter via bitmasks (no global loads in the loop) ----
    if (tid < 768) {
        const int x = (tid * 2731) >> 16;
        const int y = tid - x * 24;
        float a[26];
#pragma unroll
        for (int c = 0; c < 26; ++c) a[c] = 0.f;
        a[9] = 1.f;
        uint32_t mlo = mw[x] & mw[64 + y];
        uint32_t mhi = mw[32 + x] & mw[88 + y];
#pragma unroll 1
        for (int half = 0; half < 2; ++half) {
            uint32_t mm = half ? mhi : mlo;
            const int rb = half ? 32 : 0;
            while (mm) {
                const int r = rb + __builtin_ctz(mm);
                mm &= mm - 1;
                const int cell = (x - rpl[3 * r]) * 6 + (y - rpl[3 * r + 1]);
                const uint32_t w = (cell < 32) ? mkl[r] : mkh[r];
                if ((w >> (cell & 31)) & 1u) {
                    a[0] += 1.f;
                    const uint32_t bits = ch8[r * 36 + cell];
#pragma unroll
                    for (int c = 0; c < 8; ++c)
                        a[1 + c] += (float)((bits >> c) & 1u);
                    const float* er = embl + r * 17;
#pragma unroll
                    for (int e = 0; e < 16; ++e) a[10 + e] += er[e];
                }
            }
        }
        const int row = x * 28 + y + 2;
        const int swz = SWZ64(row);
#pragma unroll
        for (int cg = 0; cg < 4; ++cg) {
            float c[8];
#pragma unroll
            for (int j = 0; j < 8; ++j) {
                const int ci = cg * 8 + j;
                c[j] = (ci < 26) ? a[(ci < 26) ? ci : 0] : 0.f;
            }
            uint2 p0, p1;
            p0.x = pkbf(c[0], c[1]); p0.y = pkbf(c[2], c[3]);
            p1.x = pkbf(c[4], c[5]); p1.y = pkbf(c[6], c[7]);
            const int a0 = X0_OFF + (((row << 6) | (cg << 4)) ^ swz);
            *(uint2*)(smem + a0)     = p0;
            *(uint2*)(smem + a0 + 8) = p1;
        }
    } else {
        const int base = (tid - 768) * 2;                   // X0 y-pad rows
#pragma unroll
        for (int k = 0; k < 2; ++k) {
            const int u = base + k;
            const int rowi = u >> 2, slot = u & 3;
            const int x = rowi >> 2, yp = rowi & 3;
            const int row = x * 28 + ((yp < 2) ? yp : yp + 24);
            *(v8s*)(smem + X0_OFF + (((row << 6) | (slot << 4)) ^ SWZ64(row))) =
                (v8s){0,0,0,0,0,0,0,0};
        }
    }
    __syncthreads();

    // per-thread MFMA geometry
    const int l = tid & 63, wv = tid >> 6, kg = l >> 4;
    int px[3], py[3];
#pragma unroll
    for (int i = 0; i < 3; ++i) {
        const int p = (wv + 16 * i) * 16 + (l & 15);
        const int x = (p * 2731) >> 16;
        px[i] = x; py[i] = p - x * 24;
    }

    // ---- P2: conv0 (26->32, 5x5) + X1 pad zero ----
    {
        if (tid < 256) {
            const int rowi = tid >> 2, slot = tid & 3;
            const int x = rowi >> 1;
            const int rowp = x * 26 + ((rowi & 1) ? 25 : 0);
            *(v8s*)(smem + X1_OFF + (((rowp << 6) | (slot << 4)) ^ SWZ64(rowp))) =
                (v8s){0,0,0,0,0,0,0,0};
        }
        v4f acc[2][3];
#pragma unroll
        for (int m = 0; m < 2; ++m)
#pragma unroll
            for (int i = 0; i < 3; ++i) acc[m][i] = (v4f){0.f,0.f,0.f,0.f};
        conv_core<2,1,25,5,2, X0_OFF,6,28, WS0_U,2>(smem, wsv, l, px, py, acc);
        conv_epi<2,0,2, X1_OFF,6,26,1>(smem, b0, acc, px, py, kg);
    }
    __syncthreads();

    // ---- P3: conv1 (32->64, 3x3) + X2 pad zero ----
    {
        if (tid < 512) {
            const int rowi = tid >> 3, slot = tid & 7;
            const int x = rowi >> 1;
            const int rowp = x * 26 + ((rowi & 1) ? 25 : 0);
            *(v8s*)(smem + X2_OFF + (((rowp << 7) | (slot << 4)) ^ ((rowp & 7) << 4))) =
                (v8s){0,0,0,0,0,0,0,0};
        }
        v4f acc[4][3];
#pragma unroll
        for (int m = 0; m < 4; ++m)
#pragma unroll
            for (int i = 0; i < 3; ++i) acc[m][i] = (v4f){0.f,0.f,0.f,0.f};
        conv_core<4,1,9,3,1, X1_OFF,6,26, WS1_U,4>(smem, wsv, l, px, py, acc);
        conv_epi<4,0,4, X2_OFF,7,26,1>(smem, b1, acc, px, py, kg);
    }
    __syncthreads();

    // ---- P4: conv2 (64->64, 3x3) single K-sweep; split-region epilogue; ONE gather ----
    {
        v4f acc[4][3];
#pragma unroll
        for (int m = 0; m < 4; ++m)
#pragma unroll
            for (int i = 0; i < 3; ++i) acc[m][i] = (v4f){0.f,0.f,0.f,0.f};
        conv_core<4,2,9,3,1, X2_OFF,7,26, WS2_U,4>(smem, wsv, l, px, py, acc);
        conv_epi<4,0,2, X3A_OFF,6,24,0>(smem, b2, acc, px, py, kg);  // half0: X1-dead region
        __syncthreads();                                             // drain X2 reads
        conv_epi<4,2,4, X3B_OFF,6,24,0>(smem, b2, acc, px, py, kg);  // half1: X2 region
        __syncthreads();
    }
    // single gather: 512 threads, thread (gr, gg) -> 8 channels, straight to Ya in LDS
    if (tid < 512) {
        const int gr = tid >> 3, gg = tid & 7;
        const int gl = gg & 3;
        const int roff = (gg < 4) ? X3A_OFF : X3B_OFF;
        const int pxr = rpl[3 * gr], pyr = rpl[3 * gr + 1];
        const uint32_t mlo = mkl[gr], mhi = mkh[gr];
        float s0=0,s1=0,s2=0,s3=0,s4=0,s5=0,s6=0,s7=0;
#pragma unroll
        for (int cell = 0; cell < 36; ++cell) {
            const uint32_t w = (cell < 32) ? mlo : mhi;
            if ((w >> (cell & 31)) & 1u) {
                const int p = (pxr + cell / 6) * 24 + pyr + (cell % 6);
                const v8s v = *(const v8s*)(smem + roff +
                    (((p << 6) | (gl << 4)) ^ SWZ64(p)));
                s0 += b2f((uint16_t)v[0]);
                s1 += b2f((uint16_t)v[1]);
                s2 += b2f((uint16_t)v[2]);
                s3 += b2f((uint16_t)v[3]);
                s4 += b2f((uint16_t)v[4]);
                s5 += b2f((uint16_t)v[5]);
                s6 += b2f((uint16_t)v[6]);
                s7 += b2f((uint16_t)v[7]);
            }
        }
        const int base = gr * 256 + gl * 32 + (gg >> 2) * 128;
        const int swz = (gr & 7) << 4;
        *(v4f*)(smem + YA_OFF + (base ^ swz))        = (v4f){s0, s1, s2, s3};
        *(v4f*)(smem + YA_OFF + ((base + 16) ^ swz)) = (v4f){s4, s5, s6, s7};
    }
    __syncthreads();

    // ---- P6: 3-layer room MLP (f32), all in LDS ----
    mlp_layer<true >(smem, YA_OFF, YB_OFF, rw0, rb0, tid);
    __syncthreads();
    mlp_layer<true >(smem, YB_OFF, YA_OFF, rw1, rb1, tid);
    __syncthreads();
    mlp_layer<false>(smem, YA_OFF, YB_OFF, rw2, rb2, tid);
    __syncthreads();

    // ---- P7: coalesced output store ----
    {
        const int r = tid >> 4, cg = tid & 15;
        const int swz = (r & 7) << 4;
        const v4f v = *(const v4f*)(smem + YB_OFF + ((r * 256 + cg * 16) ^ swz));
        *(v4f*)(out + n * 4096 + r * 64 + cg * 4) = v;
    }
}

extern "C" void kernel_launch(void* const* d_in, const int* in_sizes, int n_in,
                              void* d_out, int out_size, void* d_ws, size_t ws_size,
                              hipStream_t stream) {
    const int*   rpos  = (const int*)  d_in[0];
    const float* rooms = (const float*)d_in[1];
    const float* emb   = (const float*)d_in[2];
    const float* w0    = (const float*)d_in[3];
    const float* b0    = (const float*)d_in[4];
    const float* w1    = (const float*)d_in[5];
    const float* b1    = (const float*)d_in[6];
    const float* w2    = (const float*)d_in[7];
    const float* b2    = (const float*)d_in[8];
    const float* rw0   = (const float*)d_in[9];
    const float* rb0   = (const float*)d_in[10];
    const float* rw1   = (const float*)d_in[11];
    const float* rb1   = (const float*)d_in[12];
    const float* rw2   = (const float*)d_in[13];
    const float* rb2   = (const float*)d_in[14];
    float* out = (float*)d_out;
    uint8_t* ws = (uint8_t*)d_ws;

    const int n = in_sizes[0] / 128;   // samples (512)
    hipLaunchKernelGGL(prep_all, dim3(50), dim3(256), 0, stream,
                       w0, w1, w2, rooms, ws);
    hipLaunchKernelGGL(fused_main, dim3(n), dim3(TPB), 0, stream,
                       rpos, rooms, emb, b0, b1, b2,
                       rw0, rb0, rw1, rb1, rw2, rb2, ws, out);
}